// Round 14
// baseline (247.011 us; speedup 1.0000x reference)
//
#include <hip/hip_runtime.h>
#include <stdint.h>

#define BB 2
#define SS 2048
#define MM 2048
#define NQ 16
#define NKV 4
#define HH 128
#define KVB 64

typedef __attribute__((ext_vector_type(4))) float f32x4;
typedef __attribute__((ext_vector_type(16))) float f32x16;
typedef _Float16 f16x8 __attribute__((ext_vector_type(8)));
typedef _Float16 f16x4 __attribute__((ext_vector_type(4)));
typedef _Float16 f16x2 __attribute__((ext_vector_type(2)));
typedef unsigned int uint4v __attribute__((ext_vector_type(4)));

__device__ __forceinline__ void gll16(const _Float16* g, _Float16* l) {
  __builtin_amdgcn_global_load_lds(
      (__attribute__((address_space(1))) void*)g,
      (__attribute__((address_space(3))) void*)l, 16, 0, 0);
}

__device__ __forceinline__ float fexp2(float x) {
#if __has_builtin(__builtin_amdgcn_exp2f)
  return __builtin_amdgcn_exp2f(x);   // raw v_exp_f32
#else
  float r;
  asm("v_exp_f32 %0, %1" : "=v"(r) : "v"(x));
  return r;
#endif
}

__device__ __forceinline__ unsigned int pkrtz(float a, float b) {
  return __builtin_bit_cast(unsigned int, __builtin_amdgcn_cvt_pkrtz(a, b));
}

// ---------------- fp32 -> fp16 convert (vectorized) ----------------
__global__ __launch_bounds__(256) void k_f32_to_f16(const float* __restrict__ in,
                                                    _Float16* __restrict__ out, int n4) {
  int i = blockIdx.x * 256 + threadIdx.x;
  if (i >= n4) return;
  float4 v = ((const float4*)in)[i];
  f16x4 o = { (_Float16)v.x, (_Float16)v.y, (_Float16)v.z, (_Float16)v.w };
  ((f16x4*)out)[i] = o;
}

// ------------- fused weight transposes: z selects {Wq,Wk,Wv,Wo} -------------
__global__ __launch_bounds__(256) void k_wtrans(
    const float* __restrict__ Wq, const float* __restrict__ Wk,
    const float* __restrict__ Wv, const float* __restrict__ Wo,
    _Float16* __restrict__ Wqkvt, _Float16* __restrict__ Wot) {
  const int z = blockIdx.z;
  if ((z == 1 || z == 2) && blockIdx.y >= 16) return;
  const float* in = (z == 0) ? Wq : (z == 1) ? Wk : (z == 2) ? Wv : Wo;
  _Float16* out = (z == 3) ? Wot : Wqkvt;
  const int N_in = (z == 1 || z == 2) ? 512 : 2048;
  const int n_off = (z == 1) ? 2048 : (z == 2) ? 2560 : 0;

  __shared__ float tile[32][33];
  const int k0 = blockIdx.x * 32;
  const int n0 = blockIdx.y * 32;
  const int tx = threadIdx.x & 31;
  const int ty = threadIdx.x >> 5;
  #pragma unroll
  for (int r = ty; r < 32; r += 8)
    tile[r][tx] = in[(size_t)(k0 + r) * N_in + n0 + tx];
  __syncthreads();
  #pragma unroll
  for (int r = ty; r < 32; r += 8)
    out[(size_t)(n0 + r + n_off) * 2048 + k0 + tx] = (_Float16)tile[tx][r];
}

// ------------- V transpose: qkv[b*S+s][2560+hv*128+h] -> VtG[(b*NKV+hv)*H+h][s] -------------
__global__ __launch_bounds__(256) void k_vtrans(const _Float16* __restrict__ qkv,
                                                _Float16* __restrict__ VtG) {
  __shared__ _Float16 tile[32][33];
  const int s0 = blockIdx.x * 32;
  const int z = blockIdx.y;
  const int h0 = (z & 3) * 32;
  const int bv = z >> 2;
  const int b = bv >> 2;
  const int hv = bv & 3;
  const int tx = threadIdx.x & 31;
  const int ty = threadIdx.x >> 5;
  #pragma unroll
  for (int r = ty; r < 32; r += 8)
    tile[r][tx] = qkv[(size_t)(b * SS + s0 + r) * 3072 + 2560 + hv * 128 + h0 + tx];
  __syncthreads();
  #pragma unroll
  for (int r = ty; r < 32; r += 8)
    VtG[((size_t)bv * HH + h0 + r) * SS + s0 + tx] = tile[tx][r];
}

// ============ 256xBN MFMA GEMM, 2 merged phases per K-tile (round-13 state) ============
template <int FN, bool F16OUT>
__global__ __launch_bounds__(512, 2) void k_gemm256(
    const _Float16* __restrict__ A, const _Float16* __restrict__ Bt,
    void* __restrict__ Cout, int NT_M, int N, int K) {
  __shared__ _Float16 As[2][256 * 64];
  __shared__ _Float16 Bs[2][FN * 64 * 64];

  const int tid = threadIdx.x;
  const int w = tid >> 6;
  const int l = tid & 63;
  const int lr = l & 15;
  const int al4 = l >> 4;
  const int wr = w >> 2;
  const int wc = w & 3;
  const int swz = (lr & 7) << 4;

  const int nwg = gridDim.x;
  const int bid = blockIdx.x;
  const int sbid = (bid & 7) * (nwg >> 3) + (bid >> 3);
  const int bm = (sbid % NT_M) * 256;
  const int bn = (sbid / NT_M) * (FN * 64);
  const int KT = K >> 6;

  const int srow = tid >> 3;
  const int sch = (tid & 7) ^ (srow & 7);
  const _Float16* aSrc = A + (size_t)(bm + srow) * K + sch * 8;
  const _Float16* bSrc = Bt + (size_t)(bn + srow) * K + sch * 8;

  auto stA = [&](int buf, int r, int kt) {
    gll16(aSrc + (size_t)(r * 64) * K + kt * 64, &As[buf][r * 4096 + w * 512]);
  };
  auto stB = [&](int buf, int r, int kt) {
    gll16(bSrc + (size_t)(r * 64) * K + kt * 64, &Bs[buf][r * 4096 + w * 512]);
  };

  f32x4 acc[8][FN] = {};

  stA(0, 0, 0); stA(0, 1, 0); stA(0, 2, 0); stA(0, 3, 0);
  stB(0, 0, 0); stB(0, 1, 0);
  if (FN == 3) stB(0, 2, 0);
  if (KT > 1) {
    stA(1, 0, 1); stA(1, 2, 1); stB(1, 0, 1); stB(1, 1, 1);
    asm volatile("s_waitcnt vmcnt(4)" ::: "memory");
  } else {
    asm volatile("s_waitcnt vmcnt(0)" ::: "memory");
  }
  __builtin_amdgcn_s_barrier();

  for (int t = 0; t < KT; ++t) {
    const int cb = t & 1;
    const char* Ab = (const char*)&As[cb][0];
    const char* Bb = (const char*)&Bs[cb][0];
    f16x8 bF[FN][2];
    #pragma unroll
    for (int ph = 0; ph < 2; ++ph) {
      f16x8 aF[4][2];
      #pragma unroll
      for (int fm = 0; fm < 4; ++fm)
        #pragma unroll
        for (int ks = 0; ks < 2; ++ks) {
          const int row = wr * 128 + (ph * 4 + fm) * 16 + lr;
          aF[fm][ks] = *(const f16x8*)(Ab + row * 128 + (((ks * 4 + al4) * 16) ^ swz));
        }
      if (ph == 0) {
        #pragma unroll
        for (int fn = 0; fn < FN; ++fn)
          #pragma unroll
          for (int ks = 0; ks < 2; ++ks) {
            const int col = wc * (FN * 16) + fn * 16 + lr;
            bF[fn][ks] = *(const f16x8*)(Bb + col * 128 + (((ks * 4 + al4) * 16) ^ swz));
          }
      }
      if (ph == 0 && t + 1 < KT) {
        if (FN == 3) stB(cb ^ 1, 2, t + 1);
        stA(cb ^ 1, 1, t + 1); stA(cb ^ 1, 3, t + 1);
      }
      if (ph == 1 && t + 2 < KT) {
        stA(cb, 0, t + 2); stA(cb, 2, t + 2);
        stB(cb, 0, t + 2); stB(cb, 1, t + 2);
      }
      __builtin_amdgcn_s_barrier();
      asm volatile("s_waitcnt lgkmcnt(0)" ::: "memory");
      __builtin_amdgcn_sched_barrier(0);
      __builtin_amdgcn_s_setprio(1);
      #pragma unroll
      for (int fm = 0; fm < 4; ++fm)
        #pragma unroll
        for (int fn = 0; fn < FN; ++fn)
          #pragma unroll
          for (int ks = 0; ks < 2; ++ks)
            acc[ph * 4 + fm][fn] = __builtin_amdgcn_mfma_f32_16x16x32_f16(
                aF[fm][ks], bF[fn][ks], acc[ph * 4 + fm][fn], 0, 0, 0);
      __builtin_amdgcn_s_setprio(0);
      __builtin_amdgcn_sched_barrier(0);
      if (ph == 0) {
        __builtin_amdgcn_s_barrier();
      } else {
        if (t + 2 < KT) asm volatile("s_waitcnt vmcnt(4)" ::: "memory");
        else            asm volatile("s_waitcnt vmcnt(0)" ::: "memory");
        __builtin_amdgcn_s_barrier();
      }
    }
  }

  #pragma unroll
  for (int fm = 0; fm < 8; ++fm) {
    #pragma unroll
    for (int i = 0; i < 4; ++i) {
      const int row = bm + wr * 128 + fm * 16 + al4 * 4 + i;
      #pragma unroll
      for (int fn = 0; fn < FN; ++fn) {
        const int col = bn + wc * (FN * 16) + fn * 16 + lr;
        if (F16OUT)
          ((_Float16*)Cout)[(size_t)row * N + col] = (_Float16)acc[fm][fn][i];
        else
          ((float*)Cout)[(size_t)row * N + col] = acc[fm][fn][i];
      }
    }
  }
}

// ---------------- fused RMSNorm + RoPE + scatter (Q, K only) ----------------
__global__ __launch_bounds__(256) void k_normrope(
    const _Float16* __restrict__ qkv,
    const float* __restrict__ q_scale, const float* __restrict__ k_scale,
    _Float16* __restrict__ Qr, _Float16* __restrict__ Kr) {
  const int row = blockIdx.x;
  const int b = row >> 11;
  const int s = row & 2047;
  const int hh = blockIdx.y * 4 + (threadIdx.x >> 6);
  const int l = threadIdx.x & 63;
  const _Float16* src = qkv + (size_t)row * 3072 + hh * 128 + l * 2;
  float x0 = (float)src[0];
  float x1 = (float)src[1];
  float ssum = x0 * x0 + x1 * x1;
  #pragma unroll
  for (int d = 1; d < 64; d <<= 1) ssum += __shfl_xor(ssum, d);
  const float rstd = rsqrtf(ssum * (1.f / 128.f) + 1e-6f);
  const float* scl = (hh < 16) ? q_scale : k_scale;
  x0 *= rstd * scl[2 * l];
  x1 *= rstd * scl[2 * l + 1];
  const float y0 = __shfl_xor(x0, 32);
  const float y1 = __shfl_xor(x1, 32);
  const int j0 = (2 * l) & 63;
  const float kLog = 0.20762050593046014f;
  const float f0 = (float)s * exp2f(-(float)j0 * kLog);
  const float f1 = (float)s * exp2f(-(float)(j0 + 1) * kLog);
  const float c0 = cosf(f0), s0 = sinf(f0);
  const float c1 = cosf(f1), s1 = sinf(f1);
  float r0, r1;
  if (l < 32) { r0 = x0 * c0 - y0 * s0; r1 = x1 * c1 - y1 * s1; }
  else        { r0 = x0 * c0 + y0 * s0; r1 = x1 * c1 + y1 * s1; }
  if (hh < 16) {
    _Float16* dst = Qr + ((size_t)(b * NQ + hh) * SS + s) * HH + 2 * l;
    dst[0] = (_Float16)r0; dst[1] = (_Float16)r1;
  } else {
    _Float16* dst = Kr + ((size_t)(b * NKV + (hh - 16)) * SS + s) * HH + 2 * l;
    dst[0] = (_Float16)r0; dst[1] = (_Float16)r1;
  }
}

// ---- causal GQA flash attention: single LDS buffer + T14 reg-staged prefetch ----
// Loads for tile t+1 issue BEFORE compute(t) (latency hides under MFMA/VALU);
// ds_write lands after the post-compute barrier. 3 blocks/CU preserved.
__device__ const unsigned char g_tasks[24] = {
  61, 63, 28,
  57, 59, 53, 55, 24,
  49, 51, 45, 47, 20,
  41, 43, 37, 39, 16,
  33, 35, 12,
  8, 4, 0
};

__global__ __launch_bounds__(256, 3) void k_attn(
    const _Float16* __restrict__ Qr, const _Float16* __restrict__ Kr,
    const _Float16* __restrict__ VtG,
    const float* __restrict__ qs, const float* __restrict__ ks,
    float* __restrict__ PartA, float* __restrict__ PartB,
    float* __restrict__ psA, float* __restrict__ psB,
    _Float16* __restrict__ Ao) {
  __shared__ _Float16 Ks[KVB * 128];   // 16KB, XOR-swizzled content
  __shared__ _Float16 Vs[128 * KVB];   // 16KB

  const int tid = threadIdx.x;
  const int w = tid >> 6;
  const int l = tid & 63;
  const int l31 = l & 31;
  const int hi = l >> 5;
  const int sw7 = (l31 & 7) << 4;
  const int bu = blockIdx.x;
  const int b = bu >> 4, u = bu & 15;
  const int kvh = u >> 2;

  const int task = g_tasks[blockIdx.y];
  const int heavy = task & 1;
  const int half = (task >> 1) & 1;
  const int qt = task >> 2;
  const int q0 = qt * 128;
  const int halfLen = qt + 1;
  const int t0 = heavy ? half * halfLen : 0;
  const int t1 = heavy ? t0 + halfLen : 2 * qt + 2;

  float ma = fmaxf(fabsf(qs[l]), fabsf(qs[l + 64]));
  float mb = fmaxf(fabsf(ks[l]), fabsf(ks[l + 64]));
  #pragma unroll
  for (int d = 1; d < 64; d <<= 1) {
    ma = fmaxf(ma, __shfl_xor(ma, d));
    mb = fmaxf(mb, __shfl_xor(mb, d));
  }
  const float M2 = 1.4426950408889634f * ma * mb;
  const float K2 = 0.12752982260735795f; // log2(e)/sqrt(128)

  const _Float16* Kbase = Kr + (size_t)(b * NKV + kvh) * SS * HH;
  const _Float16* Vbase = VtG + (size_t)(b * NKV + kvh) * HH * SS;

  f16x8 qf[8];
  {
    const _Float16* qp = Qr + ((size_t)(b * NQ + u) * SS + q0 + w * 32 + l31) * HH + hi * 8;
    #pragma unroll
    for (int hs = 0; hs < 8; hs++) {
      qf[hs] = *(const f16x8*)(qp + hs * 16);
      qf[hs] *= (_Float16)K2;
    }
  }

  f32x16 acc0 = {}, acc1 = {}, acc2 = {}, acc3 = {};
  float psum = 0.f;

  // per-thread staging addresses (pre-inverse-swizzled source, linear LDS dst)
  const int krow0 = tid >> 4, kc0 = (tid & 15) ^ (krow0 & 7);
  const int vrow0 = tid >> 3, vc0 = (tid & 7) ^ (vrow0 & 7);
  uint4v kreg[4], vreg[4];

  auto loadT = [&](int t) {
    const int kv0 = t * KVB;
    #pragma unroll
    for (int it = 0; it < 4; it++) {
      const int krow = krow0 + it * 16;             // n=it*256+tid: row=n>>4
      const int vrow = vrow0 + it * 32;             // row=n>>3
      kreg[it] = *(const uint4v*)(Kbase + (size_t)(kv0 + krow) * HH + kc0 * 8);
      vreg[it] = *(const uint4v*)(Vbase + (size_t)vrow * SS + kv0 + vc0 * 8);
    }
  };
  auto writeT = [&]() {
    #pragma unroll
    for (int it = 0; it < 4; it++) {
      *(uint4v*)(&Ks[(size_t)(it * 256 + tid) * 8]) = kreg[it];
      *(uint4v*)(&Vs[(size_t)(it * 256 + tid) * 8]) = vreg[it];
    }
  };

  const int qwb = q0 + w * 32;
  const int qlane = qwb + l31;

  loadT(t0);
  writeT();
  __syncthreads();

  for (int t = t0; t < t1; t++) {
    const bool hasNext = (t + 1 < t1);
    if (hasNext) loadT(t + 1);          // issue early; hides under compute below
    const int kv0 = t * KVB;
    if (kv0 <= qwb + 31) {
      const char* Kb = (const char*)&Ks[0];
      const char* Vb = (const char*)&Vs[0];

      f32x16 S0 = {}, S1 = {};
      __builtin_amdgcn_s_setprio(1);
      #pragma unroll
      for (int hs = 0; hs < 8; hs++) {
        const int ch = hs * 2 + hi;
        f16x8 k0 = *(const f16x8*)(Kb + l31 * 256 + ((ch << 4) ^ sw7));
        f16x8 k1 = *(const f16x8*)(Kb + (32 + l31) * 256 + ((ch << 4) ^ sw7));
        S0 = __builtin_amdgcn_mfma_f32_32x32x16_f16(k0, qf[hs], S0, 0, 0, 0);
        S1 = __builtin_amdgcn_mfma_f32_32x32x16_f16(k1, qf[hs], S1, 0, 0, 0);
      }
      __builtin_amdgcn_s_setprio(0);

      const bool domask = (kv0 + 63 > qwb);
      float p0[16], p1[16];
      #pragma unroll
      for (int r = 0; r < 16; r++) {
        const int cr = (r & 3) + 8 * (r >> 2) + 4 * hi;
        float e0 = fexp2(S0[r] - M2);
        float e1 = fexp2(S1[r] - M2);
        if (domask) {
          if (kv0 + cr > qlane) e0 = 0.f;
          if (kv0 + 32 + cr > qlane) e1 = 0.f;
        }
        p0[r] = e0; p1[r] = e1;
        psum += e0 + e1;
      }

      unsigned int pkv[4][4];
      #pragma unroll
      for (int g = 0; g < 4; g++) {
        pkv[0][g] = pkrtz(p0[2 * g], p0[2 * g + 1]);
        pkv[1][g] = pkrtz(p0[8 + 2 * g], p0[9 + 2 * g]);
        pkv[2][g] = pkrtz(p1[2 * g], p1[2 * g + 1]);
        pkv[3][g] = pkrtz(p1[8 + 2 * g], p1[9 + 2 * g]);
      }
      f16x8 pa[4];
      #pragma unroll
      for (int ksx = 0; ksx < 4; ksx++) {
        unsigned int a0 = pkv[ksx][0], a1 = pkv[ksx][1], a2 = pkv[ksx][2], a3 = pkv[ksx][3];
        unsigned int x0 = (unsigned int)__shfl_xor((int)a0, 32);
        unsigned int x1 = (unsigned int)__shfl_xor((int)a1, 32);
        unsigned int x2 = (unsigned int)__shfl_xor((int)a2, 32);
        unsigned int x3 = (unsigned int)__shfl_xor((int)a3, 32);
        uint4v dv;
        dv.x = hi ? x2 : a0;
        dv.y = hi ? x3 : a1;
        dv.z = hi ? a2 : x0;
        dv.w = hi ? a3 : x1;
        pa[ksx] = __builtin_bit_cast(f16x8, dv);
      }

      __builtin_amdgcn_s_setprio(1);
      #pragma unroll
      for (int ksx = 0; ksx < 4; ksx++) {
        const int ch = ksx * 2 + hi;
        f16x8 v0 = *(const f16x8*)(Vb + (0 * 32 + l31) * 128 + ((ch << 4) ^ sw7));
        acc0 = __builtin_amdgcn_mfma_f32_32x32x16_f16(pa[ksx], v0, acc0, 0, 0, 0);
        f16x8 v1 = *(const f16x8*)(Vb + (1 * 32 + l31) * 128 + ((ch << 4) ^ sw7));
        acc1 = __builtin_amdgcn_mfma_f32_32x32x16_f16(pa[ksx], v1, acc1, 0, 0, 0);
        f16x8 v2 = *(const f16x8*)(Vb + (2 * 32 + l31) * 128 + ((ch << 4) ^ sw7));
        acc2 = __builtin_amdgcn_mfma_f32_32x32x16_f16(pa[ksx], v2, acc2, 0, 0, 0);
        f16x8 v3 = *(const f16x8*)(Vb + (3 * 32 + l31) * 128 + ((ch << 4) ^ sw7));
        acc3 = __builtin_amdgcn_mfma_f32_32x32x16_f16(pa[ksx], v3, acc3, 0, 0, 0);
      }
      __builtin_amdgcn_s_setprio(0);
    }
    __syncthreads();                     // all waves done reading Ks/Vs
    if (hasNext) writeT();               // compiler waits vmcnt on kreg/vreg here
    __syncthreads();                     // writes visible before next compute
  }

  const float tot = psum + __shfl_xor(psum, 32);
  if (heavy) {
    const int slot = bu * 8 + (qt - 8);
    float* pPart = (half ? PartB : PartA) + (size_t)slot * 16384;
    float* sPart = (half ? psB : psA) + slot * 128;
    if (hi == 0) sPart[w * 32 + l31] = tot;
    #pragma unroll
    for (int r = 0; r < 16; r++) {
      const int cr = (r & 3) + 8 * (r >> 2) + 4 * hi;
      float* dst = pPart + (size_t)(w * 32 + cr) * 128 + l31;
      dst[0]  = acc0[r];
      dst[32] = acc1[r];
      dst[64] = acc2[r];
      dst[96] = acc3[r];
    }
  } else {
    const float inv = 1.f / tot;
    #pragma unroll
    for (int r = 0; r < 16; r++) {
      const int cr = (r & 3) + 8 * (r >> 2) + 4 * hi;
      const float ivr = __shfl(inv, cr);
      _Float16* dst = Ao + ((size_t)(b * SS + q0 + w * 32 + cr)) * MM + u * HH + l31;
      dst[0]  = (_Float16)(acc0[r] * ivr);
      dst[32] = (_Float16)(acc1[r] * ivr);
      dst[64] = (_Float16)(acc2[r] * ivr);
      dst[96] = (_Float16)(acc3[r] * ivr);
    }
  }
}

// ---------------- combine heavy-strip partials -> Ao f16 ----------------
__global__ __launch_bounds__(256) void k_fin(
    const float* __restrict__ PartA, const float* __restrict__ PartB,
    const float* __restrict__ psA, const float* __restrict__ psB,
    _Float16* __restrict__ Ao) {
  const int slot = blockIdx.x;
  const int bu = slot >> 3, st = slot & 7;
  const int b = bu >> 4, u = bu & 15;
  const int qt = st + 8;
  const float* pa = PartA + (size_t)slot * 16384;
  const float* pb = PartB + (size_t)slot * 16384;
  const float* sa = psA + slot * 128;
  const float* sb = psB + slot * 128;
  #pragma unroll
  for (int it = 0; it < 16; it++) {
    const int unit = it * 256 + threadIdx.x;
    const int qr = unit >> 5, cg = unit & 31;
    const float inv = 1.f / (sa[qr] + sb[qr]);
    f32x4 va = *(const f32x4*)(pa + qr * 128 + cg * 4);
    f32x4 vb = *(const f32x4*)(pb + qr * 128 + cg * 4);
    f16x4 o = { (_Float16)((va[0] + vb[0]) * inv), (_Float16)((va[1] + vb[1]) * inv),
                (_Float16)((va[2] + vb[2]) * inv), (_Float16)((va[3] + vb[3]) * inv) };
    *(f16x4*)(Ao + ((size_t)(b * SS + qt * 128 + qr)) * MM + u * HH + cg * 4) = o;
  }
}

// ---------------- launcher ----------------
extern "C" void kernel_launch(void* const* d_in, const int* in_sizes, int n_in,
                              void* d_out, int out_size, void* d_ws, size_t ws_size,
                              hipStream_t stream) {
  const float* hidden = (const float*)d_in[0];
  const float* Wq = (const float*)d_in[2];
  const float* Wk = (const float*)d_in[3];
  const float* Wv = (const float*)d_in[4];
  const float* Wo = (const float*)d_in[5];
  const float* q_scale = (const float*)d_in[6];
  const float* k_scale = (const float*)d_in[7];

  char* ws = (char*)d_ws;
  _Float16* Xb    = (_Float16*)(ws);               // 4096x2048      16.78 MB (dead after GEMM1)
  _Float16* Wqkvt = (_Float16*)(ws + 16777216);    // 3072x2048      12.58 MB
  _Float16* Wot   = (_Float16*)(ws + 29360128);    // 2048x2048       8.39 MB
  _Float16* qkv   = (_Float16*)(ws + 37748736);    // 4096x3072      25.17 MB (dead after vtrans)
  _Float16* Qr    = (_Float16*)(ws + 62914560);    // 2x16x2048x128  16.78 MB
  _Float16* Kr    = (_Float16*)(ws + 79691776);    // 2x4x2048x128    4.19 MB
  _Float16* VtG   = (_Float16*)(ws + 83886080);    // 2x4x128x2048    4.19 MB
  _Float16* Ao    = (_Float16*)(ws + 88080384);    // 4096x2048      16.78 MB
  float*    PartB = (float*)(ws);                  // over Xb
  float*    PartA = (float*)(ws + 37748736);       // over qkv
  float*    psA   = (float*)(ws + 54525952);       // 128 KB
  float*    psB   = (float*)(ws + 54657024);       // 128 KB

  k_f32_to_f16<<<dim3(8192), dim3(256), 0, stream>>>(hidden, Xb, 2097152);
  k_wtrans<<<dim3(64, 64, 4), dim3(256), 0, stream>>>(Wq, Wk, Wv, Wo, Wqkvt, Wot);
  k_gemm256<3, true><<<dim3(256), dim3(512), 0, stream>>>(Xb, Wqkvt, (void*)qkv, 16, 3072, 2048);
  k_normrope<<<dim3(4096, 5), dim3(256), 0, stream>>>(qkv, q_scale, k_scale, Qr, Kr);
  k_vtrans<<<dim3(64, 32), dim3(256), 0, stream>>>(qkv, VtG);
  k_attn<<<dim3(32, 24), dim3(256), 0, stream>>>(Qr, Kr, VtG, q_scale, k_scale,
                                                 PartA, PartB, psA, psB, Ao);
  k_fin<<<dim3(256), dim3(256), 0, stream>>>(PartA, PartB, psA, psB, Ao);
  k_gemm256<2, false><<<dim3(256), dim3(512), 0, stream>>>(Ao, Wot, d_out, 16, 2048, 2048);
}

// Round 15
// 210.671 us; speedup vs baseline: 1.1725x; 1.1725x over previous
//
#include <hip/hip_runtime.h>
#include <stdint.h>

#define BB 2
#define SS 2048
#define MM 2048
#define NQ 16
#define NKV 4
#define HH 128
#define KVB 64

typedef __attribute__((ext_vector_type(4))) float f32x4;
typedef __attribute__((ext_vector_type(16))) float f32x16;
typedef _Float16 f16x8 __attribute__((ext_vector_type(8)));
typedef _Float16 f16x4 __attribute__((ext_vector_type(4)));
typedef _Float16 f16x2 __attribute__((ext_vector_type(2)));
typedef unsigned int uint4v __attribute__((ext_vector_type(4)));

__device__ __forceinline__ void gll16(const _Float16* g, _Float16* l) {
  __builtin_amdgcn_global_load_lds(
      (__attribute__((address_space(1))) void*)g,
      (__attribute__((address_space(3))) void*)l, 16, 0, 0);
}

__device__ __forceinline__ float fexp2(float x) {
#if __has_builtin(__builtin_amdgcn_exp2f)
  return __builtin_amdgcn_exp2f(x);   // raw v_exp_f32
#else
  float r;
  asm("v_exp_f32 %0, %1" : "=v"(r) : "v"(x));
  return r;
#endif
}

__device__ __forceinline__ unsigned int pkrtz(float a, float b) {
  return __builtin_bit_cast(unsigned int, __builtin_amdgcn_cvt_pkrtz(a, b));
}

// ---------------- fp32 -> fp16 convert (vectorized) ----------------
__global__ __launch_bounds__(256) void k_f32_to_f16(const float* __restrict__ in,
                                                    _Float16* __restrict__ out, int n4) {
  int i = blockIdx.x * 256 + threadIdx.x;
  if (i >= n4) return;
  float4 v = ((const float4*)in)[i];
  f16x4 o = { (_Float16)v.x, (_Float16)v.y, (_Float16)v.z, (_Float16)v.w };
  ((f16x4*)out)[i] = o;
}

// ------------- fused weight transposes: z selects {Wq,Wk,Wv,Wo} -------------
__global__ __launch_bounds__(256) void k_wtrans(
    const float* __restrict__ Wq, const float* __restrict__ Wk,
    const float* __restrict__ Wv, const float* __restrict__ Wo,
    _Float16* __restrict__ Wqkvt, _Float16* __restrict__ Wot) {
  const int z = blockIdx.z;
  if ((z == 1 || z == 2) && blockIdx.y >= 16) return;
  const float* in = (z == 0) ? Wq : (z == 1) ? Wk : (z == 2) ? Wv : Wo;
  _Float16* out = (z == 3) ? Wot : Wqkvt;
  const int N_in = (z == 1 || z == 2) ? 512 : 2048;
  const int n_off = (z == 1) ? 2048 : (z == 2) ? 2560 : 0;

  __shared__ float tile[32][33];
  const int k0 = blockIdx.x * 32;
  const int n0 = blockIdx.y * 32;
  const int tx = threadIdx.x & 31;
  const int ty = threadIdx.x >> 5;
  #pragma unroll
  for (int r = ty; r < 32; r += 8)
    tile[r][tx] = in[(size_t)(k0 + r) * N_in + n0 + tx];
  __syncthreads();
  #pragma unroll
  for (int r = ty; r < 32; r += 8)
    out[(size_t)(n0 + r + n_off) * 2048 + k0 + tx] = (_Float16)tile[tx][r];
}

// ------------- V transpose: qkv[b*S+s][2560+hv*128+h] -> VtG[(b*NKV+hv)*H+h][s] -------------
__global__ __launch_bounds__(256) void k_vtrans(const _Float16* __restrict__ qkv,
                                                _Float16* __restrict__ VtG) {
  __shared__ _Float16 tile[32][33];
  const int s0 = blockIdx.x * 32;
  const int z = blockIdx.y;
  const int h0 = (z & 3) * 32;
  const int bv = z >> 2;
  const int b = bv >> 2;
  const int hv = bv & 3;
  const int tx = threadIdx.x & 31;
  const int ty = threadIdx.x >> 5;
  #pragma unroll
  for (int r = ty; r < 32; r += 8)
    tile[r][tx] = qkv[(size_t)(b * SS + s0 + r) * 3072 + 2560 + hv * 128 + h0 + tx];
  __syncthreads();
  #pragma unroll
  for (int r = ty; r < 32; r += 8)
    VtG[((size_t)bv * HH + h0 + r) * SS + s0 + tx] = tile[tx][r];
}

// ============ 256xBN MFMA GEMM, 2 merged phases per K-tile (round-13 state) ============
template <int FN, bool F16OUT>
__global__ __launch_bounds__(512, 2) void k_gemm256(
    const _Float16* __restrict__ A, const _Float16* __restrict__ Bt,
    void* __restrict__ Cout, int NT_M, int N, int K) {
  __shared__ _Float16 As[2][256 * 64];
  __shared__ _Float16 Bs[2][FN * 64 * 64];

  const int tid = threadIdx.x;
  const int w = tid >> 6;
  const int l = tid & 63;
  const int lr = l & 15;
  const int al4 = l >> 4;
  const int wr = w >> 2;
  const int wc = w & 3;
  const int swz = (lr & 7) << 4;

  const int nwg = gridDim.x;
  const int bid = blockIdx.x;
  const int sbid = (bid & 7) * (nwg >> 3) + (bid >> 3);
  const int bm = (sbid % NT_M) * 256;
  const int bn = (sbid / NT_M) * (FN * 64);
  const int KT = K >> 6;

  const int srow = tid >> 3;
  const int sch = (tid & 7) ^ (srow & 7);
  const _Float16* aSrc = A + (size_t)(bm + srow) * K + sch * 8;
  const _Float16* bSrc = Bt + (size_t)(bn + srow) * K + sch * 8;

  auto stA = [&](int buf, int r, int kt) {
    gll16(aSrc + (size_t)(r * 64) * K + kt * 64, &As[buf][r * 4096 + w * 512]);
  };
  auto stB = [&](int buf, int r, int kt) {
    gll16(bSrc + (size_t)(r * 64) * K + kt * 64, &Bs[buf][r * 4096 + w * 512]);
  };

  f32x4 acc[8][FN] = {};

  stA(0, 0, 0); stA(0, 1, 0); stA(0, 2, 0); stA(0, 3, 0);
  stB(0, 0, 0); stB(0, 1, 0);
  if (FN == 3) stB(0, 2, 0);
  if (KT > 1) {
    stA(1, 0, 1); stA(1, 2, 1); stB(1, 0, 1); stB(1, 1, 1);
    asm volatile("s_waitcnt vmcnt(4)" ::: "memory");
  } else {
    asm volatile("s_waitcnt vmcnt(0)" ::: "memory");
  }
  __builtin_amdgcn_s_barrier();

  for (int t = 0; t < KT; ++t) {
    const int cb = t & 1;
    const char* Ab = (const char*)&As[cb][0];
    const char* Bb = (const char*)&Bs[cb][0];
    f16x8 bF[FN][2];
    #pragma unroll
    for (int ph = 0; ph < 2; ++ph) {
      f16x8 aF[4][2];
      #pragma unroll
      for (int fm = 0; fm < 4; ++fm)
        #pragma unroll
        for (int ks = 0; ks < 2; ++ks) {
          const int row = wr * 128 + (ph * 4 + fm) * 16 + lr;
          aF[fm][ks] = *(const f16x8*)(Ab + row * 128 + (((ks * 4 + al4) * 16) ^ swz));
        }
      if (ph == 0) {
        #pragma unroll
        for (int fn = 0; fn < FN; ++fn)
          #pragma unroll
          for (int ks = 0; ks < 2; ++ks) {
            const int col = wc * (FN * 16) + fn * 16 + lr;
            bF[fn][ks] = *(const f16x8*)(Bb + col * 128 + (((ks * 4 + al4) * 16) ^ swz));
          }
      }
      if (ph == 0 && t + 1 < KT) {
        if (FN == 3) stB(cb ^ 1, 2, t + 1);
        stA(cb ^ 1, 1, t + 1); stA(cb ^ 1, 3, t + 1);
      }
      if (ph == 1 && t + 2 < KT) {
        stA(cb, 0, t + 2); stA(cb, 2, t + 2);
        stB(cb, 0, t + 2); stB(cb, 1, t + 2);
      }
      __builtin_amdgcn_s_barrier();
      asm volatile("s_waitcnt lgkmcnt(0)" ::: "memory");
      __builtin_amdgcn_sched_barrier(0);
      __builtin_amdgcn_s_setprio(1);
      #pragma unroll
      for (int fm = 0; fm < 4; ++fm)
        #pragma unroll
        for (int fn = 0; fn < FN; ++fn)
          #pragma unroll
          for (int ks = 0; ks < 2; ++ks)
            acc[ph * 4 + fm][fn] = __builtin_amdgcn_mfma_f32_16x16x32_f16(
                aF[fm][ks], bF[fn][ks], acc[ph * 4 + fm][fn], 0, 0, 0);
      __builtin_amdgcn_s_setprio(0);
      __builtin_amdgcn_sched_barrier(0);
      if (ph == 0) {
        __builtin_amdgcn_s_barrier();
      } else {
        if (t + 2 < KT) asm volatile("s_waitcnt vmcnt(4)" ::: "memory");
        else            asm volatile("s_waitcnt vmcnt(0)" ::: "memory");
        __builtin_amdgcn_s_barrier();
      }
    }
  }

  #pragma unroll
  for (int fm = 0; fm < 8; ++fm) {
    #pragma unroll
    for (int i = 0; i < 4; ++i) {
      const int row = bm + wr * 128 + fm * 16 + al4 * 4 + i;
      #pragma unroll
      for (int fn = 0; fn < FN; ++fn) {
        const int col = bn + wc * (FN * 16) + fn * 16 + lr;
        if (F16OUT)
          ((_Float16*)Cout)[(size_t)row * N + col] = (_Float16)acc[fm][fn][i];
        else
          ((float*)Cout)[(size_t)row * N + col] = acc[fm][fn][i];
      }
    }
  }
}

// ---------------- fused RMSNorm + RoPE + scatter (Q, K only) ----------------
__global__ __launch_bounds__(256) void k_normrope(
    const _Float16* __restrict__ qkv,
    const float* __restrict__ q_scale, const float* __restrict__ k_scale,
    _Float16* __restrict__ Qr, _Float16* __restrict__ Kr) {
  const int row = blockIdx.x;
  const int b = row >> 11;
  const int s = row & 2047;
  const int hh = blockIdx.y * 4 + (threadIdx.x >> 6);
  const int l = threadIdx.x & 63;
  const _Float16* src = qkv + (size_t)row * 3072 + hh * 128 + l * 2;
  float x0 = (float)src[0];
  float x1 = (float)src[1];
  float ssum = x0 * x0 + x1 * x1;
  #pragma unroll
  for (int d = 1; d < 64; d <<= 1) ssum += __shfl_xor(ssum, d);
  const float rstd = rsqrtf(ssum * (1.f / 128.f) + 1e-6f);
  const float* scl = (hh < 16) ? q_scale : k_scale;
  x0 *= rstd * scl[2 * l];
  x1 *= rstd * scl[2 * l + 1];
  const float y0 = __shfl_xor(x0, 32);
  const float y1 = __shfl_xor(x1, 32);
  const int j0 = (2 * l) & 63;
  const float kLog = 0.20762050593046014f;
  const float f0 = (float)s * exp2f(-(float)j0 * kLog);
  const float f1 = (float)s * exp2f(-(float)(j0 + 1) * kLog);
  const float c0 = cosf(f0), s0 = sinf(f0);
  const float c1 = cosf(f1), s1 = sinf(f1);
  float r0, r1;
  if (l < 32) { r0 = x0 * c0 - y0 * s0; r1 = x1 * c1 - y1 * s1; }
  else        { r0 = x0 * c0 + y0 * s0; r1 = x1 * c1 + y1 * s1; }
  if (hh < 16) {
    _Float16* dst = Qr + ((size_t)(b * NQ + hh) * SS + s) * HH + 2 * l;
    dst[0] = (_Float16)r0; dst[1] = (_Float16)r1;
  } else {
    _Float16* dst = Kr + ((size_t)(b * NKV + (hh - 16)) * SS + s) * HH + 2 * l;
    dst[0] = (_Float16)r0; dst[1] = (_Float16)r1;
  }
}

// ---- causal GQA flash attention: KVB=128 macro-tiles (r13 body x2 per stage) ----
// One stage (16 gll16) + 2 barriers per 128 kv rows (was 2 stages + 4 barriers).
// K LDS [128][128hw] 256B rows; V^T LDS [128h][128kv] 256B rows; both XOR-swizzled.
__device__ const unsigned char g_tasks[24] = {
  61, 63, 28,
  57, 59, 53, 55, 24,
  49, 51, 45, 47, 20,
  41, 43, 37, 39, 16,
  33, 35, 12,
  8, 4, 0
};

__global__ __launch_bounds__(256, 2) void k_attn(
    const _Float16* __restrict__ Qr, const _Float16* __restrict__ Kr,
    const _Float16* __restrict__ VtG,
    const float* __restrict__ qs, const float* __restrict__ ks,
    float* __restrict__ PartA, float* __restrict__ PartB,
    float* __restrict__ psA, float* __restrict__ psB,
    _Float16* __restrict__ Ao) {
  __shared__ _Float16 Ks[128 * 128];   // 32KB
  __shared__ _Float16 Vs[128 * 128];   // 32KB

  const int tid = threadIdx.x;
  const int w = tid >> 6;
  const int l = tid & 63;
  const int l31 = l & 31;
  const int hi = l >> 5;
  const int sw7 = (l31 & 7) << 4;
  const int bu = blockIdx.x;
  const int b = bu >> 4, u = bu & 15;
  const int kvh = u >> 2;

  const int task = g_tasks[blockIdx.y];
  const int heavy = task & 1;
  const int half = (task >> 1) & 1;
  const int qt = task >> 2;
  const int q0 = qt * 128;
  const int total = 2 * qt + 2;                 // 64-unit tiles (even)
  const int h0 = ((qt + 2) >> 1) << 1;          // even split point
  const int t0 = heavy ? (half ? h0 : 0) : 0;
  const int t1 = heavy ? (half ? total : h0) : total;

  float ma = fmaxf(fabsf(qs[l]), fabsf(qs[l + 64]));
  float mb = fmaxf(fabsf(ks[l]), fabsf(ks[l + 64]));
  #pragma unroll
  for (int d = 1; d < 64; d <<= 1) {
    ma = fmaxf(ma, __shfl_xor(ma, d));
    mb = fmaxf(mb, __shfl_xor(mb, d));
  }
  const float M2 = 1.4426950408889634f * ma * mb;
  const float K2 = 0.12752982260735795f; // log2(e)/sqrt(128)

  const _Float16* Kbase = Kr + (size_t)(b * NKV + kvh) * SS * HH;
  const _Float16* Vbase = VtG + (size_t)(b * NKV + kvh) * HH * SS;

  f16x8 qf[8];
  {
    const _Float16* qp = Qr + ((size_t)(b * NQ + u) * SS + q0 + w * 32 + l31) * HH + hi * 8;
    #pragma unroll
    for (int hs = 0; hs < 8; hs++) {
      qf[hs] = *(const f16x8*)(qp + hs * 16);
      qf[hs] *= (_Float16)K2;
    }
  }

  f32x16 acc0 = {}, acc1 = {}, acc2 = {}, acc3 = {};
  float psum = 0.f;

  // stage 128 kv rows: K 128x256B (2048 chunks) + V^T 128x256B (2048 chunks)
  auto stage = [&](int m) {
    const int kv0 = m * KVB;
    #pragma unroll
    for (int it = 0; it < 8; it++) {
      const int n = it * 256 + tid;
      const int row = n >> 4, c = n & 15;
      const int cs = c ^ (row & 7);
      gll16(Kbase + (size_t)(kv0 + row) * HH + cs * 8,
            &Ks[(size_t)(it * 256 + w * 64) * 8]);
      gll16(Vbase + (size_t)row * SS + kv0 + cs * 8,
            &Vs[(size_t)(it * 256 + w * 64) * 8]);
    }
  };

  const int qwb = q0 + w * 32;
  const int qlane = qwb + l31;

  for (int m = t0; m < t1; m += 2) {
    stage(m);
    __syncthreads();           // drain vmcnt + tile visible
    const char* Kb = (const char*)&Ks[0];
    const char* Vb = (const char*)&Vs[0];
    #pragma unroll
    for (int hh2 = 0; hh2 < 2; ++hh2) {
      const int kv0 = m * KVB + hh2 * 64;
      if (kv0 <= qwb + 31) {
        f32x16 S0 = {}, S1 = {};
        __builtin_amdgcn_s_setprio(1);
        #pragma unroll
        for (int hs = 0; hs < 8; hs++) {
          const int ch = hs * 2 + hi;
          f16x8 k0 = *(const f16x8*)(Kb + (hh2 * 64 + l31) * 256 + ((ch << 4) ^ sw7));
          f16x8 k1 = *(const f16x8*)(Kb + (hh2 * 64 + 32 + l31) * 256 + ((ch << 4) ^ sw7));
          S0 = __builtin_amdgcn_mfma_f32_32x32x16_f16(k0, qf[hs], S0, 0, 0, 0);
          S1 = __builtin_amdgcn_mfma_f32_32x32x16_f16(k1, qf[hs], S1, 0, 0, 0);
        }
        __builtin_amdgcn_s_setprio(0);

        const bool domask = (kv0 + 63 > qwb);
        float p0[16], p1[16];
        #pragma unroll
        for (int r = 0; r < 16; r++) {
          const int cr = (r & 3) + 8 * (r >> 2) + 4 * hi;
          float e0 = fexp2(S0[r] - M2);
          float e1 = fexp2(S1[r] - M2);
          if (domask) {
            if (kv0 + cr > qlane) e0 = 0.f;
            if (kv0 + 32 + cr > qlane) e1 = 0.f;
          }
          p0[r] = e0; p1[r] = e1;
          psum += e0 + e1;
        }

        unsigned int pkv[4][4];
        #pragma unroll
        for (int g = 0; g < 4; g++) {
          pkv[0][g] = pkrtz(p0[2 * g], p0[2 * g + 1]);
          pkv[1][g] = pkrtz(p0[8 + 2 * g], p0[9 + 2 * g]);
          pkv[2][g] = pkrtz(p1[2 * g], p1[2 * g + 1]);
          pkv[3][g] = pkrtz(p1[8 + 2 * g], p1[9 + 2 * g]);
        }
        f16x8 pa[4];
        #pragma unroll
        for (int ksx = 0; ksx < 4; ksx++) {
          unsigned int a0 = pkv[ksx][0], a1 = pkv[ksx][1], a2 = pkv[ksx][2], a3 = pkv[ksx][3];
          unsigned int x0 = (unsigned int)__shfl_xor((int)a0, 32);
          unsigned int x1 = (unsigned int)__shfl_xor((int)a1, 32);
          unsigned int x2 = (unsigned int)__shfl_xor((int)a2, 32);
          unsigned int x3 = (unsigned int)__shfl_xor((int)a3, 32);
          uint4v dv;
          dv.x = hi ? x2 : a0;
          dv.y = hi ? x3 : a1;
          dv.z = hi ? a2 : x0;
          dv.w = hi ? a3 : x1;
          pa[ksx] = __builtin_bit_cast(f16x8, dv);
        }

        __builtin_amdgcn_s_setprio(1);
        #pragma unroll
        for (int ksx = 0; ksx < 4; ksx++) {
          const int ch = hh2 * 8 + ksx * 2 + hi;
          f16x8 v0 = *(const f16x8*)(Vb + (0 * 32 + l31) * 256 + ((ch << 4) ^ sw7));
          acc0 = __builtin_amdgcn_mfma_f32_32x32x16_f16(pa[ksx], v0, acc0, 0, 0, 0);
          f16x8 v1 = *(const f16x8*)(Vb + (1 * 32 + l31) * 256 + ((ch << 4) ^ sw7));
          acc1 = __builtin_amdgcn_mfma_f32_32x32x16_f16(pa[ksx], v1, acc1, 0, 0, 0);
          f16x8 v2 = *(const f16x8*)(Vb + (2 * 32 + l31) * 256 + ((ch << 4) ^ sw7));
          acc2 = __builtin_amdgcn_mfma_f32_32x32x16_f16(pa[ksx], v2, acc2, 0, 0, 0);
          f16x8 v3 = *(const f16x8*)(Vb + (3 * 32 + l31) * 256 + ((ch << 4) ^ sw7));
          acc3 = __builtin_amdgcn_mfma_f32_32x32x16_f16(pa[ksx], v3, acc3, 0, 0, 0);
        }
        __builtin_amdgcn_s_setprio(0);
      }
    }
    __syncthreads();           // all reads done before next overwrite
  }

  const float tot = psum + __shfl_xor(psum, 32);
  if (heavy) {
    const int slot = bu * 8 + (qt - 8);
    float* pPart = (half ? PartB : PartA) + (size_t)slot * 16384;
    float* sPart = (half ? psB : psA) + slot * 128;
    if (hi == 0) sPart[w * 32 + l31] = tot;
    #pragma unroll
    for (int r = 0; r < 16; r++) {
      const int cr = (r & 3) + 8 * (r >> 2) + 4 * hi;
      float* dst = pPart + (size_t)(w * 32 + cr) * 128 + l31;
      dst[0]  = acc0[r];
      dst[32] = acc1[r];
      dst[64] = acc2[r];
      dst[96] = acc3[r];
    }
  } else {
    const float inv = 1.f / tot;
    #pragma unroll
    for (int r = 0; r < 16; r++) {
      const int cr = (r & 3) + 8 * (r >> 2) + 4 * hi;
      const float ivr = __shfl(inv, cr);
      _Float16* dst = Ao + ((size_t)(b * SS + q0 + w * 32 + cr)) * MM + u * HH + l31;
      dst[0]  = (_Float16)(acc0[r] * ivr);
      dst[32] = (_Float16)(acc1[r] * ivr);
      dst[64] = (_Float16)(acc2[r] * ivr);
      dst[96] = (_Float16)(acc3[r] * ivr);
    }
  }
}

// ---------------- combine heavy-strip partials -> Ao f16 ----------------
__global__ __launch_bounds__(256) void k_fin(
    const float* __restrict__ PartA, const float* __restrict__ PartB,
    const float* __restrict__ psA, const float* __restrict__ psB,
    _Float16* __restrict__ Ao) {
  const int slot = blockIdx.x;
  const int bu = slot >> 3, st = slot & 7;
  const int b = bu >> 4, u = bu & 15;
  const int qt = st + 8;
  const float* pa = PartA + (size_t)slot * 16384;
  const float* pb = PartB + (size_t)slot * 16384;
  const float* sa = psA + slot * 128;
  const float* sb = psB + slot * 128;
  #pragma unroll
  for (int it = 0; it < 16; it++) {
    const int unit = it * 256 + threadIdx.x;
    const int qr = unit >> 5, cg = unit & 31;
    const float inv = 1.f / (sa[qr] + sb[qr]);
    f32x4 va = *(const f32x4*)(pa + qr * 128 + cg * 4);
    f32x4 vb = *(const f32x4*)(pb + qr * 128 + cg * 4);
    f16x4 o = { (_Float16)((va[0] + vb[0]) * inv), (_Float16)((va[1] + vb[1]) * inv),
                (_Float16)((va[2] + vb[2]) * inv), (_Float16)((va[3] + vb[3]) * inv) };
    *(f16x4*)(Ao + ((size_t)(b * SS + qt * 128 + qr)) * MM + u * HH + cg * 4) = o;
  }
}

// ---------------- launcher ----------------
extern "C" void kernel_launch(void* const* d_in, const int* in_sizes, int n_in,
                              void* d_out, int out_size, void* d_ws, size_t ws_size,
                              hipStream_t stream) {
  const float* hidden = (const float*)d_in[0];
  const float* Wq = (const float*)d_in[2];
  const float* Wk = (const float*)d_in[3];
  const float* Wv = (const float*)d_in[4];
  const float* Wo = (const float*)d_in[5];
  const float* q_scale = (const float*)d_in[6];
  const float* k_scale = (const float*)d_in[7];

  char* ws = (char*)d_ws;
  _Float16* Xb    = (_Float16*)(ws);               // 4096x2048      16.78 MB (dead after GEMM1)
  _Float16* Wqkvt = (_Float16*)(ws + 16777216);    // 3072x2048      12.58 MB
  _Float16* Wot   = (_Float16*)(ws + 29360128);    // 2048x2048       8.39 MB
  _Float16* qkv   = (_Float16*)(ws + 37748736);    // 4096x3072      25.17 MB (dead after vtrans)
  _Float16* Qr    = (_Float16*)(ws + 62914560);    // 2x16x2048x128  16.78 MB
  _Float16* Kr    = (_Float16*)(ws + 79691776);    // 2x4x2048x128    4.19 MB
  _Float16* VtG   = (_Float16*)(ws + 83886080);    // 2x4x128x2048    4.19 MB
  _Float16* Ao    = (_Float16*)(ws + 88080384);    // 4096x2048      16.78 MB
  float*    PartB = (float*)(ws);                  // over Xb
  float*    PartA = (float*)(ws + 37748736);       // over qkv
  float*    psA   = (float*)(ws + 54525952);       // 128 KB
  float*    psB   = (float*)(ws + 54657024);       // 128 KB

  k_f32_to_f16<<<dim3(8192), dim3(256), 0, stream>>>(hidden, Xb, 2097152);
  k_wtrans<<<dim3(64, 64, 4), dim3(256), 0, stream>>>(Wq, Wk, Wv, Wo, Wqkvt, Wot);
  k_gemm256<3, true><<<dim3(256), dim3(512), 0, stream>>>(Xb, Wqkvt, (void*)qkv, 16, 3072, 2048);
  k_normrope<<<dim3(4096, 5), dim3(256), 0, stream>>>(qkv, q_scale, k_scale, Qr, Kr);
  k_vtrans<<<dim3(64, 32), dim3(256), 0, stream>>>(qkv, VtG);
  k_attn<<<dim3(32, 24), dim3(256), 0, stream>>>(Qr, Kr, VtG, q_scale, k_scale,
                                                 PartA, PartB, psA, psB, Ao);
  k_fin<<<dim3(256), dim3(256), 0, stream>>>(PartA, PartB, psA, psB, Ao);
  k_gemm256<2, false><<<dim3(256), dim3(512), 0, stream>>>(Ao, Wot, d_out, 16, 2048, 2048);
}

// Round 16
// 205.484 us; speedup vs baseline: 1.2021x; 1.0252x over previous
//
#include <hip/hip_runtime.h>
#include <stdint.h>

#define BB 2
#define SS 2048
#define MM 2048
#define NQ 16
#define NKV 4
#define HH 128
#define KVB 64

typedef __attribute__((ext_vector_type(4))) float f32x4;
typedef __attribute__((ext_vector_type(16))) float f32x16;
typedef _Float16 f16x8 __attribute__((ext_vector_type(8)));
typedef _Float16 f16x4 __attribute__((ext_vector_type(4)));
typedef _Float16 f16x2 __attribute__((ext_vector_type(2)));
typedef unsigned int uint4v __attribute__((ext_vector_type(4)));

__device__ __forceinline__ void gll16(const _Float16* g, _Float16* l) {
  __builtin_amdgcn_global_load_lds(
      (__attribute__((address_space(1))) void*)g,
      (__attribute__((address_space(3))) void*)l, 16, 0, 0);
}

__device__ __forceinline__ float fexp2(float x) {
#if __has_builtin(__builtin_amdgcn_exp2f)
  return __builtin_amdgcn_exp2f(x);   // raw v_exp_f32
#else
  float r;
  asm("v_exp_f32 %0, %1" : "=v"(r) : "v"(x));
  return r;
#endif
}

__device__ __forceinline__ unsigned int pkrtz(float a, float b) {
  return __builtin_bit_cast(unsigned int, __builtin_amdgcn_cvt_pkrtz(a, b));
}

// ------------- fused prep: z<4 -> weight transpose {Wq,Wk,Wv,Wo}; z>=4 -> f32->f16 convert ----
__global__ __launch_bounds__(256) void k_prep(
    const float* __restrict__ hidden,
    const float* __restrict__ Wq, const float* __restrict__ Wk,
    const float* __restrict__ Wv, const float* __restrict__ Wo,
    _Float16* __restrict__ Xb,
    _Float16* __restrict__ Wqkvt, _Float16* __restrict__ Wot) {
  const int z = blockIdx.z;
  if (z >= 4) {  // hidden f32 -> f16, 2M float4 units over 8192 virtual blocks
    const int bid = (z - 4) * 4096 + blockIdx.y * 64 + blockIdx.x;
    const int i = bid * 256 + threadIdx.x;
    float4 v = ((const float4*)hidden)[i];
    f16x4 o = { (_Float16)v.x, (_Float16)v.y, (_Float16)v.z, (_Float16)v.w };
    ((f16x4*)Xb)[i] = o;
    return;
  }
  if ((z == 1 || z == 2) && blockIdx.y >= 16) return;
  const float* in = (z == 0) ? Wq : (z == 1) ? Wk : (z == 2) ? Wv : Wo;
  _Float16* out = (z == 3) ? Wot : Wqkvt;
  const int N_in = (z == 1 || z == 2) ? 512 : 2048;
  const int n_off = (z == 1) ? 2048 : (z == 2) ? 2560 : 0;

  __shared__ float tile[32][33];
  const int k0 = blockIdx.x * 32;
  const int n0 = blockIdx.y * 32;
  const int tx = threadIdx.x & 31;
  const int ty = threadIdx.x >> 5;
  #pragma unroll
  for (int r = ty; r < 32; r += 8)
    tile[r][tx] = in[(size_t)(k0 + r) * N_in + n0 + tx];
  __syncthreads();
  #pragma unroll
  for (int r = ty; r < 32; r += 8)
    out[(size_t)(n0 + r + n_off) * 2048 + k0 + tx] = (_Float16)tile[tx][r];
}

// ============ 256xBN MFMA GEMM, 2 merged phases per K-tile (round-13 state) ============
template <int FN, bool F16OUT>
__global__ __launch_bounds__(512, 2) void k_gemm256(
    const _Float16* __restrict__ A, const _Float16* __restrict__ Bt,
    void* __restrict__ Cout, int NT_M, int N, int K) {
  __shared__ _Float16 As[2][256 * 64];
  __shared__ _Float16 Bs[2][FN * 64 * 64];

  const int tid = threadIdx.x;
  const int w = tid >> 6;
  const int l = tid & 63;
  const int lr = l & 15;
  const int al4 = l >> 4;
  const int wr = w >> 2;
  const int wc = w & 3;
  const int swz = (lr & 7) << 4;

  const int nwg = gridDim.x;
  const int bid = blockIdx.x;
  const int sbid = (bid & 7) * (nwg >> 3) + (bid >> 3);
  const int bm = (sbid % NT_M) * 256;
  const int bn = (sbid / NT_M) * (FN * 64);
  const int KT = K >> 6;

  const int srow = tid >> 3;
  const int sch = (tid & 7) ^ (srow & 7);
  const _Float16* aSrc = A + (size_t)(bm + srow) * K + sch * 8;
  const _Float16* bSrc = Bt + (size_t)(bn + srow) * K + sch * 8;

  auto stA = [&](int buf, int r, int kt) {
    gll16(aSrc + (size_t)(r * 64) * K + kt * 64, &As[buf][r * 4096 + w * 512]);
  };
  auto stB = [&](int buf, int r, int kt) {
    gll16(bSrc + (size_t)(r * 64) * K + kt * 64, &Bs[buf][r * 4096 + w * 512]);
  };

  f32x4 acc[8][FN] = {};

  stA(0, 0, 0); stA(0, 1, 0); stA(0, 2, 0); stA(0, 3, 0);
  stB(0, 0, 0); stB(0, 1, 0);
  if (FN == 3) stB(0, 2, 0);
  if (KT > 1) {
    stA(1, 0, 1); stA(1, 2, 1); stB(1, 0, 1); stB(1, 1, 1);
    asm volatile("s_waitcnt vmcnt(4)" ::: "memory");
  } else {
    asm volatile("s_waitcnt vmcnt(0)" ::: "memory");
  }
  __builtin_amdgcn_s_barrier();

  for (int t = 0; t < KT; ++t) {
    const int cb = t & 1;
    const char* Ab = (const char*)&As[cb][0];
    const char* Bb = (const char*)&Bs[cb][0];
    f16x8 bF[FN][2];
    #pragma unroll
    for (int ph = 0; ph < 2; ++ph) {
      f16x8 aF[4][2];
      #pragma unroll
      for (int fm = 0; fm < 4; ++fm)
        #pragma unroll
        for (int ks = 0; ks < 2; ++ks) {
          const int row = wr * 128 + (ph * 4 + fm) * 16 + lr;
          aF[fm][ks] = *(const f16x8*)(Ab + row * 128 + (((ks * 4 + al4) * 16) ^ swz));
        }
      if (ph == 0) {
        #pragma unroll
        for (int fn = 0; fn < FN; ++fn)
          #pragma unroll
          for (int ks = 0; ks < 2; ++ks) {
            const int col = wc * (FN * 16) + fn * 16 + lr;
            bF[fn][ks] = *(const f16x8*)(Bb + col * 128 + (((ks * 4 + al4) * 16) ^ swz));
          }
      }
      if (ph == 0 && t + 1 < KT) {
        if (FN == 3) stB(cb ^ 1, 2, t + 1);
        stA(cb ^ 1, 1, t + 1); stA(cb ^ 1, 3, t + 1);
      }
      if (ph == 1 && t + 2 < KT) {
        stA(cb, 0, t + 2); stA(cb, 2, t + 2);
        stB(cb, 0, t + 2); stB(cb, 1, t + 2);
      }
      __builtin_amdgcn_s_barrier();
      asm volatile("s_waitcnt lgkmcnt(0)" ::: "memory");
      __builtin_amdgcn_sched_barrier(0);
      __builtin_amdgcn_s_setprio(1);
      #pragma unroll
      for (int fm = 0; fm < 4; ++fm)
        #pragma unroll
        for (int fn = 0; fn < FN; ++fn)
          #pragma unroll
          for (int ks = 0; ks < 2; ++ks)
            acc[ph * 4 + fm][fn] = __builtin_amdgcn_mfma_f32_16x16x32_f16(
                aF[fm][ks], bF[fn][ks], acc[ph * 4 + fm][fn], 0, 0, 0);
      __builtin_amdgcn_s_setprio(0);
      __builtin_amdgcn_sched_barrier(0);
      if (ph == 0) {
        __builtin_amdgcn_s_barrier();
      } else {
        if (t + 2 < KT) asm volatile("s_waitcnt vmcnt(4)" ::: "memory");
        else            asm volatile("s_waitcnt vmcnt(0)" ::: "memory");
        __builtin_amdgcn_s_barrier();
      }
    }
  }

  #pragma unroll
  for (int fm = 0; fm < 8; ++fm) {
    #pragma unroll
    for (int i = 0; i < 4; ++i) {
      const int row = bm + wr * 128 + fm * 16 + al4 * 4 + i;
      #pragma unroll
      for (int fn = 0; fn < FN; ++fn) {
        const int col = bn + wc * (FN * 16) + fn * 16 + lr;
        if (F16OUT)
          ((_Float16*)Cout)[(size_t)row * N + col] = (_Float16)acc[fm][fn][i];
        else
          ((float*)Cout)[(size_t)row * N + col] = acc[fm][fn][i];
      }
    }
  }
}

// ------- fused RMSNorm + RoPE + scatter (y<5) and V transpose (y==5) -------
__global__ __launch_bounds__(256) void k_normrope(
    const _Float16* __restrict__ qkv,
    const float* __restrict__ q_scale, const float* __restrict__ k_scale,
    _Float16* __restrict__ Qr, _Float16* __restrict__ Kr,
    _Float16* __restrict__ VtG) {
  __shared__ _Float16 vtile[32][33];
  if (blockIdx.y == 5) {   // V transpose: 2048 virtual blocks
    if (blockIdx.x >= 2048) return;
    const int s0 = (blockIdx.x & 63) * 32;
    const int zz = blockIdx.x >> 6;      // 0..31
    const int h0 = (zz & 3) * 32;
    const int bv = zz >> 2;
    const int b = bv >> 2;
    const int hv = bv & 3;
    const int tx = threadIdx.x & 31;
    const int ty = threadIdx.x >> 5;
    #pragma unroll
    for (int r = ty; r < 32; r += 8)
      vtile[r][tx] = qkv[(size_t)(b * SS + s0 + r) * 3072 + 2560 + hv * 128 + h0 + tx];
    __syncthreads();
    #pragma unroll
    for (int r = ty; r < 32; r += 8)
      VtG[((size_t)bv * HH + h0 + r) * SS + s0 + tx] = vtile[tx][r];
    return;
  }
  const int row = blockIdx.x;
  const int b = row >> 11;
  const int s = row & 2047;
  const int hh = blockIdx.y * 4 + (threadIdx.x >> 6);
  const int l = threadIdx.x & 63;
  const _Float16* src = qkv + (size_t)row * 3072 + hh * 128 + l * 2;
  float x0 = (float)src[0];
  float x1 = (float)src[1];
  float ssum = x0 * x0 + x1 * x1;
  #pragma unroll
  for (int d = 1; d < 64; d <<= 1) ssum += __shfl_xor(ssum, d);
  const float rstd = rsqrtf(ssum * (1.f / 128.f) + 1e-6f);
  const float* scl = (hh < 16) ? q_scale : k_scale;
  x0 *= rstd * scl[2 * l];
  x1 *= rstd * scl[2 * l + 1];
  const float y0 = __shfl_xor(x0, 32);
  const float y1 = __shfl_xor(x1, 32);
  const int j0 = (2 * l) & 63;
  const float kLog = 0.20762050593046014f;
  const float f0 = (float)s * exp2f(-(float)j0 * kLog);
  const float f1 = (float)s * exp2f(-(float)(j0 + 1) * kLog);
  const float c0 = cosf(f0), s0 = sinf(f0);
  const float c1 = cosf(f1), s1 = sinf(f1);
  float r0, r1;
  if (l < 32) { r0 = x0 * c0 - y0 * s0; r1 = x1 * c1 - y1 * s1; }
  else        { r0 = x0 * c0 + y0 * s0; r1 = x1 * c1 + y1 * s1; }
  if (hh < 16) {
    _Float16* dst = Qr + ((size_t)(b * NQ + hh) * SS + s) * HH + 2 * l;
    dst[0] = (_Float16)r0; dst[1] = (_Float16)r1;
  } else {
    _Float16* dst = Kr + ((size_t)(b * NKV + (hh - 16)) * SS + s) * HH + 2 * l;
    dst[0] = (_Float16)r0; dst[1] = (_Float16)r1;
  }
}

// ---- causal GQA flash attention: KVB=128 macro-tiles + XCD-group swizzle ----
// 8 (b,kvh) K/V sets <-> 8 XCDs: linear block n -> group g=n&7, so all blocks
// sharing a K/V set take the same residue mod 8 (per-XCD L2 residency).
__device__ const unsigned char g_tasks[24] = {
  61, 63, 28,
  57, 59, 53, 55, 24,
  49, 51, 45, 47, 20,
  41, 43, 37, 39, 16,
  33, 35, 12,
  8, 4, 0
};

__global__ __launch_bounds__(256, 2) void k_attn(
    const _Float16* __restrict__ Qr, const _Float16* __restrict__ Kr,
    const _Float16* __restrict__ VtG,
    const float* __restrict__ qs, const float* __restrict__ ks,
    float* __restrict__ PartA, float* __restrict__ PartB,
    float* __restrict__ psA, float* __restrict__ psB,
    _Float16* __restrict__ Ao) {
  __shared__ _Float16 Ks[128 * 128];   // 32KB
  __shared__ _Float16 Vs[128 * 128];   // 32KB

  const int tid = threadIdx.x;
  const int w = tid >> 6;
  const int l = tid & 63;
  const int l31 = l & 31;
  const int hi = l >> 5;
  const int sw7 = (l31 & 7) << 4;

  // XCD-group remap: n -> (g = b*4+kvh, j = u&3, task row)
  const int n = blockIdx.y * 32 + blockIdx.x;   // 0..767
  const int g = n & 7;
  const int slot9 = n >> 3;                     // 0..95
  const int j = slot9 & 3;
  const int b = g >> 2;
  const int kvh = g & 3;
  const int u = kvh * 4 + j;
  const int bu = b * 16 + u;

  const int task = g_tasks[slot9 >> 2];
  const int heavy = task & 1;
  const int half = (task >> 1) & 1;
  const int qt = task >> 2;
  const int q0 = qt * 128;
  const int total = 2 * qt + 2;                 // 64-unit tiles (even)
  const int h0 = ((qt + 2) >> 1) << 1;          // even split point
  const int t0 = heavy ? (half ? h0 : 0) : 0;
  const int t1 = heavy ? (half ? total : h0) : total;

  float ma = fmaxf(fabsf(qs[l]), fabsf(qs[l + 64]));
  float mb = fmaxf(fabsf(ks[l]), fabsf(ks[l + 64]));
  #pragma unroll
  for (int d = 1; d < 64; d <<= 1) {
    ma = fmaxf(ma, __shfl_xor(ma, d));
    mb = fmaxf(mb, __shfl_xor(mb, d));
  }
  const float M2 = 1.4426950408889634f * ma * mb;
  const float K2 = 0.12752982260735795f; // log2(e)/sqrt(128)

  const _Float16* Kbase = Kr + (size_t)(b * NKV + kvh) * SS * HH;
  const _Float16* Vbase = VtG + (size_t)(b * NKV + kvh) * HH * SS;

  f16x8 qf[8];
  {
    const _Float16* qp = Qr + ((size_t)(b * NQ + u) * SS + q0 + w * 32 + l31) * HH + hi * 8;
    #pragma unroll
    for (int hs = 0; hs < 8; hs++) {
      qf[hs] = *(const f16x8*)(qp + hs * 16);
      qf[hs] *= (_Float16)K2;
    }
  }

  f32x16 acc0 = {}, acc1 = {}, acc2 = {}, acc3 = {};
  float psum = 0.f;

  auto stage = [&](int m) {
    const int kv0 = m * KVB;
    #pragma unroll
    for (int it = 0; it < 8; it++) {
      const int nn = it * 256 + tid;
      const int row = nn >> 4, c = nn & 15;
      const int cs = c ^ (row & 7);
      gll16(Kbase + (size_t)(kv0 + row) * HH + cs * 8,
            &Ks[(size_t)(it * 256 + w * 64) * 8]);
      gll16(Vbase + (size_t)row * SS + kv0 + cs * 8,
            &Vs[(size_t)(it * 256 + w * 64) * 8]);
    }
  };

  const int qwb = q0 + w * 32;
  const int qlane = qwb + l31;

  for (int m = t0; m < t1; m += 2) {
    stage(m);
    __syncthreads();
    const char* Kb = (const char*)&Ks[0];
    const char* Vb = (const char*)&Vs[0];
    #pragma unroll
    for (int hh2 = 0; hh2 < 2; ++hh2) {
      const int kv0 = m * KVB + hh2 * 64;
      if (kv0 <= qwb + 31) {
        f32x16 S0 = {}, S1 = {};
        __builtin_amdgcn_s_setprio(1);
        #pragma unroll
        for (int hs = 0; hs < 8; hs++) {
          const int ch = hs * 2 + hi;
          f16x8 k0 = *(const f16x8*)(Kb + (hh2 * 64 + l31) * 256 + ((ch << 4) ^ sw7));
          f16x8 k1 = *(const f16x8*)(Kb + (hh2 * 64 + 32 + l31) * 256 + ((ch << 4) ^ sw7));
          S0 = __builtin_amdgcn_mfma_f32_32x32x16_f16(k0, qf[hs], S0, 0, 0, 0);
          S1 = __builtin_amdgcn_mfma_f32_32x32x16_f16(k1, qf[hs], S1, 0, 0, 0);
        }
        __builtin_amdgcn_s_setprio(0);

        const bool domask = (kv0 + 63 > qwb);
        float p0[16], p1[16];
        #pragma unroll
        for (int r = 0; r < 16; r++) {
          const int cr = (r & 3) + 8 * (r >> 2) + 4 * hi;
          float e0 = fexp2(S0[r] - M2);
          float e1 = fexp2(S1[r] - M2);
          if (domask) {
            if (kv0 + cr > qlane) e0 = 0.f;
            if (kv0 + 32 + cr > qlane) e1 = 0.f;
          }
          p0[r] = e0; p1[r] = e1;
          psum += e0 + e1;
        }

        unsigned int pkv[4][4];
        #pragma unroll
        for (int gg = 0; gg < 4; gg++) {
          pkv[0][gg] = pkrtz(p0[2 * gg], p0[2 * gg + 1]);
          pkv[1][gg] = pkrtz(p0[8 + 2 * gg], p0[9 + 2 * gg]);
          pkv[2][gg] = pkrtz(p1[2 * gg], p1[2 * gg + 1]);
          pkv[3][gg] = pkrtz(p1[8 + 2 * gg], p1[9 + 2 * gg]);
        }
        f16x8 pa[4];
        #pragma unroll
        for (int ksx = 0; ksx < 4; ksx++) {
          unsigned int a0 = pkv[ksx][0], a1 = pkv[ksx][1], a2 = pkv[ksx][2], a3 = pkv[ksx][3];
          unsigned int x0 = (unsigned int)__shfl_xor((int)a0, 32);
          unsigned int x1 = (unsigned int)__shfl_xor((int)a1, 32);
          unsigned int x2 = (unsigned int)__shfl_xor((int)a2, 32);
          unsigned int x3 = (unsigned int)__shfl_xor((int)a3, 32);
          uint4v dv;
          dv.x = hi ? x2 : a0;
          dv.y = hi ? x3 : a1;
          dv.z = hi ? a2 : x0;
          dv.w = hi ? a3 : x1;
          pa[ksx] = __builtin_bit_cast(f16x8, dv);
        }

        __builtin_amdgcn_s_setprio(1);
        #pragma unroll
        for (int ksx = 0; ksx < 4; ksx++) {
          const int ch = hh2 * 8 + ksx * 2 + hi;
          f16x8 v0 = *(const f16x8*)(Vb + (0 * 32 + l31) * 256 + ((ch << 4) ^ sw7));
          acc0 = __builtin_amdgcn_mfma_f32_32x32x16_f16(pa[ksx], v0, acc0, 0, 0, 0);
          f16x8 v1 = *(const f16x8*)(Vb + (1 * 32 + l31) * 256 + ((ch << 4) ^ sw7));
          acc1 = __builtin_amdgcn_mfma_f32_32x32x16_f16(pa[ksx], v1, acc1, 0, 0, 0);
          f16x8 v2 = *(const f16x8*)(Vb + (2 * 32 + l31) * 256 + ((ch << 4) ^ sw7));
          acc2 = __builtin_amdgcn_mfma_f32_32x32x16_f16(pa[ksx], v2, acc2, 0, 0, 0);
          f16x8 v3 = *(const f16x8*)(Vb + (3 * 32 + l31) * 256 + ((ch << 4) ^ sw7));
          acc3 = __builtin_amdgcn_mfma_f32_32x32x16_f16(pa[ksx], v3, acc3, 0, 0, 0);
        }
        __builtin_amdgcn_s_setprio(0);
      }
    }
    __syncthreads();
  }

  const float tot = psum + __shfl_xor(psum, 32);
  if (heavy) {
    const int slot = bu * 8 + (qt - 8);
    float* pPart = (half ? PartB : PartA) + (size_t)slot * 16384;
    float* sPart = (half ? psB : psA) + slot * 128;
    if (hi == 0) sPart[w * 32 + l31] = tot;
    #pragma unroll
    for (int r = 0; r < 16; r++) {
      const int cr = (r & 3) + 8 * (r >> 2) + 4 * hi;
      float* dst = pPart + (size_t)(w * 32 + cr) * 128 + l31;
      dst[0]  = acc0[r];
      dst[32] = acc1[r];
      dst[64] = acc2[r];
      dst[96] = acc3[r];
    }
  } else {
    const float inv = 1.f / tot;
    #pragma unroll
    for (int r = 0; r < 16; r++) {
      const int cr = (r & 3) + 8 * (r >> 2) + 4 * hi;
      const float ivr = __shfl(inv, cr);
      _Float16* dst = Ao + ((size_t)(b * SS + q0 + w * 32 + cr)) * MM + u * HH + l31;
      dst[0]  = (_Float16)(acc0[r] * ivr);
      dst[32] = (_Float16)(acc1[r] * ivr);
      dst[64] = (_Float16)(acc2[r] * ivr);
      dst[96] = (_Float16)(acc3[r] * ivr);
    }
  }
}

// ---------------- combine heavy-strip partials -> Ao f16 ----------------
__global__ __launch_bounds__(256) void k_fin(
    const float* __restrict__ PartA, const float* __restrict__ PartB,
    const float* __restrict__ psA, const float* __restrict__ psB,
    _Float16* __restrict__ Ao) {
  const int slot = blockIdx.x;
  const int bu = slot >> 3, st = slot & 7;
  const int b = bu >> 4, u = bu & 15;
  const int qt = st + 8;
  const float* pa = PartA + (size_t)slot * 16384;
  const float* pb = PartB + (size_t)slot * 16384;
  const float* sa = psA + slot * 128;
  const float* sb = psB + slot * 128;
  #pragma unroll
  for (int it = 0; it < 16; it++) {
    const int unit = it * 256 + threadIdx.x;
    const int qr = unit >> 5, cg = unit & 31;
    const float inv = 1.f / (sa[qr] + sb[qr]);
    f32x4 va = *(const f32x4*)(pa + qr * 128 + cg * 4);
    f32x4 vb = *(const f32x4*)(pb + qr * 128 + cg * 4);
    f16x4 o = { (_Float16)((va[0] + vb[0]) * inv), (_Float16)((va[1] + vb[1]) * inv),
                (_Float16)((va[2] + vb[2]) * inv), (_Float16)((va[3] + vb[3]) * inv) };
    *(f16x4*)(Ao + ((size_t)(b * SS + qt * 128 + qr)) * MM + u * HH + cg * 4) = o;
  }
}

// ---------------- launcher ----------------
extern "C" void kernel_launch(void* const* d_in, const int* in_sizes, int n_in,
                              void* d_out, int out_size, void* d_ws, size_t ws_size,
                              hipStream_t stream) {
  const float* hidden = (const float*)d_in[0];
  const float* Wq = (const float*)d_in[2];
  const float* Wk = (const float*)d_in[3];
  const float* Wv = (const float*)d_in[4];
  const float* Wo = (const float*)d_in[5];
  const float* q_scale = (const float*)d_in[6];
  const float* k_scale = (const float*)d_in[7];

  char* ws = (char*)d_ws;
  _Float16* Xb    = (_Float16*)(ws);               // 4096x2048      16.78 MB (dead after GEMM1)
  _Float16* Wqkvt = (_Float16*)(ws + 16777216);    // 3072x2048      12.58 MB
  _Float16* Wot   = (_Float16*)(ws + 29360128);    // 2048x2048       8.39 MB
  _Float16* qkv   = (_Float16*)(ws + 37748736);    // 4096x3072      25.17 MB (dead after normrope)
  _Float16* Qr    = (_Float16*)(ws + 62914560);    // 2x16x2048x128  16.78 MB
  _Float16* Kr    = (_Float16*)(ws + 79691776);    // 2x4x2048x128    4.19 MB
  _Float16* VtG   = (_Float16*)(ws + 83886080);    // 2x4x128x2048    4.19 MB
  _Float16* Ao    = (_Float16*)(ws + 88080384);    // 4096x2048      16.78 MB
  float*    PartB = (float*)(ws);                  // over Xb
  float*    PartA = (float*)(ws + 37748736);       // over qkv
  float*    psA   = (float*)(ws + 54525952);       // 128 KB
  float*    psB   = (float*)(ws + 54657024);       // 128 KB

  k_prep<<<dim3(64, 64, 6), dim3(256), 0, stream>>>(hidden, Wq, Wk, Wv, Wo, Xb, Wqkvt, Wot);
  k_gemm256<3, true><<<dim3(256), dim3(512), 0, stream>>>(Xb, Wqkvt, (void*)qkv, 16, 3072, 2048);
  k_normrope<<<dim3(4096, 6), dim3(256), 0, stream>>>(qkv, q_scale, k_scale, Qr, Kr, VtG);
  k_attn<<<dim3(32, 24), dim3(256), 0, stream>>>(Qr, Kr, VtG, q_scale, k_scale,
                                                 PartA, PartB, psA, psB, Ao);
  k_fin<<<dim3(256), dim3(256), 0, stream>>>(PartA, PartB, psA, psB, Ao);
  k_gemm256<2, false><<<dim3(256), dim3(512), 0, stream>>>(Ao, Wot, d_out, 16, 2048, 2048);
}

// Round 17
// 199.331 us; speedup vs baseline: 1.2392x; 1.0309x over previous
//
#include <hip/hip_runtime.h>
#include <stdint.h>

#define BB 2
#define SS 2048
#define MM 2048
#define NQ 16
#define NKV 4
#define HH 128
#define KVB 64

typedef __attribute__((ext_vector_type(4))) float f32x4;
typedef __attribute__((ext_vector_type(16))) float f32x16;
typedef _Float16 f16x8 __attribute__((ext_vector_type(8)));
typedef _Float16 f16x4 __attribute__((ext_vector_type(4)));
typedef _Float16 f16x2 __attribute__((ext_vector_type(2)));
typedef unsigned int uint4v __attribute__((ext_vector_type(4)));

__device__ __forceinline__ void gll16(const _Float16* g, _Float16* l) {
  __builtin_amdgcn_global_load_lds(
      (__attribute__((address_space(1))) void*)g,
      (__attribute__((address_space(3))) void*)l, 16, 0, 0);
}

__device__ __forceinline__ float fexp2(float x) {
#if __has_builtin(__builtin_amdgcn_exp2f)
  return __builtin_amdgcn_exp2f(x);   // raw v_exp_f32
#else
  float r;
  asm("v_exp_f32 %0, %1" : "=v"(r) : "v"(x));
  return r;
#endif
}

// sin/cos of (2*pi*rev) via raw v_sin/v_cos (input in revolutions, fract-reduced)
__device__ __forceinline__ float fsin2pi(float rev) {
  float f, s;
  asm("v_fract_f32 %0, %1" : "=v"(f) : "v"(rev));
  asm("v_sin_f32 %0, %1" : "=v"(s) : "v"(f));
  return s;
}
__device__ __forceinline__ float fcos2pi(float rev) {
  float f, c;
  asm("v_fract_f32 %0, %1" : "=v"(f) : "v"(rev));
  asm("v_cos_f32 %0, %1" : "=v"(c) : "v"(f));
  return c;
}

__device__ __forceinline__ unsigned int pkrtz(float a, float b) {
  return __builtin_bit_cast(unsigned int, __builtin_amdgcn_cvt_pkrtz(a, b));
}

// ------------- fused prep: z<4 -> weight transpose {Wq,Wk,Wv,Wo}; z>=4 -> f32->f16 convert ----
__global__ __launch_bounds__(256) void k_prep(
    const float* __restrict__ hidden,
    const float* __restrict__ Wq, const float* __restrict__ Wk,
    const float* __restrict__ Wv, const float* __restrict__ Wo,
    _Float16* __restrict__ Xb,
    _Float16* __restrict__ Wqkvt, _Float16* __restrict__ Wot) {
  const int z = blockIdx.z;
  if (z >= 4) {  // hidden f32 -> f16
    const int bid = (z - 4) * 4096 + blockIdx.y * 64 + blockIdx.x;
    const int i = bid * 256 + threadIdx.x;
    float4 v = ((const float4*)hidden)[i];
    f16x4 o = { (_Float16)v.x, (_Float16)v.y, (_Float16)v.z, (_Float16)v.w };
    ((f16x4*)Xb)[i] = o;
    return;
  }
  if ((z == 1 || z == 2) && blockIdx.y >= 16) return;
  const float* in = (z == 0) ? Wq : (z == 1) ? Wk : (z == 2) ? Wv : Wo;
  _Float16* out = (z == 3) ? Wot : Wqkvt;
  const int N_in = (z == 1 || z == 2) ? 512 : 2048;
  const int n_off = (z == 1) ? 2048 : (z == 2) ? 2560 : 0;

  __shared__ float tile[32][33];
  const int k0 = blockIdx.x * 32;
  const int n0 = blockIdx.y * 32;
  const int tx = threadIdx.x & 31;
  const int ty = threadIdx.x >> 5;
  #pragma unroll
  for (int r = ty; r < 32; r += 8)
    tile[r][tx] = in[(size_t)(k0 + r) * N_in + n0 + tx];
  __syncthreads();
  #pragma unroll
  for (int r = ty; r < 32; r += 8)
    out[(size_t)(n0 + r + n_off) * 2048 + k0 + tx] = (_Float16)tile[tx][r];
}

// ============ 256xBN MFMA GEMM, 2 merged phases per K-tile (round-13 state) ============
template <int FN, bool F16OUT>
__global__ __launch_bounds__(512, 2) void k_gemm256(
    const _Float16* __restrict__ A, const _Float16* __restrict__ Bt,
    void* __restrict__ Cout, int NT_M, int N, int K) {
  __shared__ _Float16 As[2][256 * 64];
  __shared__ _Float16 Bs[2][FN * 64 * 64];

  const int tid = threadIdx.x;
  const int w = tid >> 6;
  const int l = tid & 63;
  const int lr = l & 15;
  const int al4 = l >> 4;
  const int wr = w >> 2;
  const int wc = w & 3;
  const int swz = (lr & 7) << 4;

  const int nwg = gridDim.x;
  const int bid = blockIdx.x;
  const int sbid = (bid & 7) * (nwg >> 3) + (bid >> 3);
  const int bm = (sbid % NT_M) * 256;
  const int bn = (sbid / NT_M) * (FN * 64);
  const int KT = K >> 6;

  const int srow = tid >> 3;
  const int sch = (tid & 7) ^ (srow & 7);
  const _Float16* aSrc = A + (size_t)(bm + srow) * K + sch * 8;
  const _Float16* bSrc = Bt + (size_t)(bn + srow) * K + sch * 8;

  auto stA = [&](int buf, int r, int kt) {
    gll16(aSrc + (size_t)(r * 64) * K + kt * 64, &As[buf][r * 4096 + w * 512]);
  };
  auto stB = [&](int buf, int r, int kt) {
    gll16(bSrc + (size_t)(r * 64) * K + kt * 64, &Bs[buf][r * 4096 + w * 512]);
  };

  f32x4 acc[8][FN] = {};

  stA(0, 0, 0); stA(0, 1, 0); stA(0, 2, 0); stA(0, 3, 0);
  stB(0, 0, 0); stB(0, 1, 0);
  if (FN == 3) stB(0, 2, 0);
  if (KT > 1) {
    stA(1, 0, 1); stA(1, 2, 1); stB(1, 0, 1); stB(1, 1, 1);
    asm volatile("s_waitcnt vmcnt(4)" ::: "memory");
  } else {
    asm volatile("s_waitcnt vmcnt(0)" ::: "memory");
  }
  __builtin_amdgcn_s_barrier();

  for (int t = 0; t < KT; ++t) {
    const int cb = t & 1;
    const char* Ab = (const char*)&As[cb][0];
    const char* Bb = (const char*)&Bs[cb][0];
    f16x8 bF[FN][2];
    #pragma unroll
    for (int ph = 0; ph < 2; ++ph) {
      f16x8 aF[4][2];
      #pragma unroll
      for (int fm = 0; fm < 4; ++fm)
        #pragma unroll
        for (int ks = 0; ks < 2; ++ks) {
          const int row = wr * 128 + (ph * 4 + fm) * 16 + lr;
          aF[fm][ks] = *(const f16x8*)(Ab + row * 128 + (((ks * 4 + al4) * 16) ^ swz));
        }
      if (ph == 0) {
        #pragma unroll
        for (int fn = 0; fn < FN; ++fn)
          #pragma unroll
          for (int ks = 0; ks < 2; ++ks) {
            const int col = wc * (FN * 16) + fn * 16 + lr;
            bF[fn][ks] = *(const f16x8*)(Bb + col * 128 + (((ks * 4 + al4) * 16) ^ swz));
          }
      }
      if (ph == 0 && t + 1 < KT) {
        if (FN == 3) stB(cb ^ 1, 2, t + 1);
        stA(cb ^ 1, 1, t + 1); stA(cb ^ 1, 3, t + 1);
      }
      if (ph == 1 && t + 2 < KT) {
        stA(cb, 0, t + 2); stA(cb, 2, t + 2);
        stB(cb, 0, t + 2); stB(cb, 1, t + 2);
      }
      __builtin_amdgcn_s_barrier();
      asm volatile("s_waitcnt lgkmcnt(0)" ::: "memory");
      __builtin_amdgcn_sched_barrier(0);
      __builtin_amdgcn_s_setprio(1);
      #pragma unroll
      for (int fm = 0; fm < 4; ++fm)
        #pragma unroll
        for (int fn = 0; fn < FN; ++fn)
          #pragma unroll
          for (int ks = 0; ks < 2; ++ks)
            acc[ph * 4 + fm][fn] = __builtin_amdgcn_mfma_f32_16x16x32_f16(
                aF[fm][ks], bF[fn][ks], acc[ph * 4 + fm][fn], 0, 0, 0);
      __builtin_amdgcn_s_setprio(0);
      __builtin_amdgcn_sched_barrier(0);
      if (ph == 0) {
        __builtin_amdgcn_s_barrier();
      } else {
        if (t + 2 < KT) asm volatile("s_waitcnt vmcnt(4)" ::: "memory");
        else            asm volatile("s_waitcnt vmcnt(0)" ::: "memory");
        __builtin_amdgcn_s_barrier();
      }
    }
  }

  #pragma unroll
  for (int fm = 0; fm < 8; ++fm) {
    #pragma unroll
    for (int i = 0; i < 4; ++i) {
      const int row = bm + wr * 128 + fm * 16 + al4 * 4 + i;
      #pragma unroll
      for (int fn = 0; fn < FN; ++fn) {
        const int col = bn + wc * (FN * 16) + fn * 16 + lr;
        if (F16OUT)
          ((_Float16*)Cout)[(size_t)row * N + col] = (_Float16)acc[fm][fn][i];
        else
          ((float*)Cout)[(size_t)row * N + col] = acc[fm][fn][i];
      }
    }
  }
}

// ------- fused RMSNorm + RoPE + scatter (y<5) and V transpose (y==5), fast trig -------
__global__ __launch_bounds__(256) void k_normrope(
    const _Float16* __restrict__ qkv,
    const float* __restrict__ q_scale, const float* __restrict__ k_scale,
    _Float16* __restrict__ Qr, _Float16* __restrict__ Kr,
    _Float16* __restrict__ VtG) {
  __shared__ _Float16 vtile[32][33];
  if (blockIdx.y == 5) {   // V transpose
    if (blockIdx.x >= 2048) return;
    const int s0 = (blockIdx.x & 63) * 32;
    const int zz = blockIdx.x >> 6;
    const int h0 = (zz & 3) * 32;
    const int bv = zz >> 2;
    const int b = bv >> 2;
    const int hv = bv & 3;
    const int tx = threadIdx.x & 31;
    const int ty = threadIdx.x >> 5;
    #pragma unroll
    for (int r = ty; r < 32; r += 8)
      vtile[r][tx] = qkv[(size_t)(b * SS + s0 + r) * 3072 + 2560 + hv * 128 + h0 + tx];
    __syncthreads();
    #pragma unroll
    for (int r = ty; r < 32; r += 8)
      VtG[((size_t)bv * HH + h0 + r) * SS + s0 + tx] = vtile[tx][r];
    return;
  }
  const int row = blockIdx.x;
  const int b = row >> 11;
  const int s = row & 2047;
  const int hh = blockIdx.y * 4 + (threadIdx.x >> 6);
  const int l = threadIdx.x & 63;
  const _Float16* src = qkv + (size_t)row * 3072 + hh * 128 + l * 2;
  float x0 = (float)src[0];
  float x1 = (float)src[1];
  float ssum = x0 * x0 + x1 * x1;
  #pragma unroll
  for (int d = 1; d < 64; d <<= 1) ssum += __shfl_xor(ssum, d);
  const float rstd = rsqrtf(ssum * (1.f / 128.f) + 1e-6f);
  const float* scl = (hh < 16) ? q_scale : k_scale;
  x0 *= rstd * scl[2 * l];
  x1 *= rstd * scl[2 * l + 1];
  const float y0 = __shfl_xor(x0, 32);
  const float y1 = __shfl_xor(x1, 32);
  const int j0 = (2 * l) & 63;
  const float kLog = 0.20762050593046014f;          // log2(10000)/64
  const float inv2pi = 0.15915494309189535f;
  // rev = s * 10000^(-j/64) / (2*pi); fast v_exp + v_fract + v_sin/v_cos
  const float rev0 = (float)s * fexp2(-(float)j0 * kLog) * inv2pi;
  const float rev1 = (float)s * fexp2(-(float)(j0 + 1) * kLog) * inv2pi;
  const float c0 = fcos2pi(rev0), s0 = fsin2pi(rev0);
  const float c1 = fcos2pi(rev1), s1 = fsin2pi(rev1);
  float r0, r1;
  if (l < 32) { r0 = x0 * c0 - y0 * s0; r1 = x1 * c1 - y1 * s1; }
  else        { r0 = x0 * c0 + y0 * s0; r1 = x1 * c1 + y1 * s1; }
  if (hh < 16) {
    _Float16* dst = Qr + ((size_t)(b * NQ + hh) * SS + s) * HH + 2 * l;
    dst[0] = (_Float16)r0; dst[1] = (_Float16)r1;
  } else {
    _Float16* dst = Kr + ((size_t)(b * NKV + (hh - 16)) * SS + s) * HH + 2 * l;
    dst[0] = (_Float16)r0; dst[1] = (_Float16)r1;
  }
}

// ---- causal GQA flash attention: KVB=128 macro-tiles + XCD-group swizzle ----
__device__ const unsigned char g_tasks[24] = {
  61, 63, 28,
  57, 59, 53, 55, 24,
  49, 51, 45, 47, 20,
  41, 43, 37, 39, 16,
  33, 35, 12,
  8, 4, 0
};

__global__ __launch_bounds__(256, 2) void k_attn(
    const _Float16* __restrict__ Qr, const _Float16* __restrict__ Kr,
    const _Float16* __restrict__ VtG,
    const float* __restrict__ qs, const float* __restrict__ ks,
    float* __restrict__ PartA, float* __restrict__ PartB,
    float* __restrict__ psA, float* __restrict__ psB,
    _Float16* __restrict__ Ao) {
  __shared__ _Float16 Ks[128 * 128];   // 32KB
  __shared__ _Float16 Vs[128 * 128];   // 32KB

  const int tid = threadIdx.x;
  const int w = tid >> 6;
  const int l = tid & 63;
  const int l31 = l & 31;
  const int hi = l >> 5;
  const int sw7 = (l31 & 7) << 4;

  const int n = blockIdx.y * 32 + blockIdx.x;   // 0..767
  const int g = n & 7;
  const int slot9 = n >> 3;                     // 0..95
  const int j = slot9 & 3;
  const int b = g >> 2;
  const int kvh = g & 3;
  const int u = kvh * 4 + j;
  const int bu = b * 16 + u;

  const int task = g_tasks[slot9 >> 2];
  const int heavy = task & 1;
  const int half = (task >> 1) & 1;
  const int qt = task >> 2;
  const int q0 = qt * 128;
  const int total = 2 * qt + 2;
  const int h0 = ((qt + 2) >> 1) << 1;
  const int t0 = heavy ? (half ? h0 : 0) : 0;
  const int t1 = heavy ? (half ? total : h0) : total;

  float ma = fmaxf(fabsf(qs[l]), fabsf(qs[l + 64]));
  float mb = fmaxf(fabsf(ks[l]), fabsf(ks[l + 64]));
  #pragma unroll
  for (int d = 1; d < 64; d <<= 1) {
    ma = fmaxf(ma, __shfl_xor(ma, d));
    mb = fmaxf(mb, __shfl_xor(mb, d));
  }
  const float M2 = 1.4426950408889634f * ma * mb;
  const float K2 = 0.12752982260735795f; // log2(e)/sqrt(128)

  const _Float16* Kbase = Kr + (size_t)(b * NKV + kvh) * SS * HH;
  const _Float16* Vbase = VtG + (size_t)(b * NKV + kvh) * HH * SS;

  f16x8 qf[8];
  {
    const _Float16* qp = Qr + ((size_t)(b * NQ + u) * SS + q0 + w * 32 + l31) * HH + hi * 8;
    #pragma unroll
    for (int hs = 0; hs < 8; hs++) {
      qf[hs] = *(const f16x8*)(qp + hs * 16);
      qf[hs] *= (_Float16)K2;
    }
  }

  f32x16 acc0 = {}, acc1 = {}, acc2 = {}, acc3 = {};
  float psum = 0.f;

  auto stage = [&](int m) {
    const int kv0 = m * KVB;
    #pragma unroll
    for (int it = 0; it < 8; it++) {
      const int nn = it * 256 + tid;
      const int row = nn >> 4, c = nn & 15;
      const int cs = c ^ (row & 7);
      gll16(Kbase + (size_t)(kv0 + row) * HH + cs * 8,
            &Ks[(size_t)(it * 256 + w * 64) * 8]);
      gll16(Vbase + (size_t)row * SS + kv0 + cs * 8,
            &Vs[(size_t)(it * 256 + w * 64) * 8]);
    }
  };

  const int qwb = q0 + w * 32;
  const int qlane = qwb + l31;

  for (int m = t0; m < t1; m += 2) {
    stage(m);
    __syncthreads();
    const char* Kb = (const char*)&Ks[0];
    const char* Vb = (const char*)&Vs[0];
    #pragma unroll
    for (int hh2 = 0; hh2 < 2; ++hh2) {
      const int kv0 = m * KVB + hh2 * 64;
      if (kv0 <= qwb + 31) {
        f32x16 S0 = {}, S1 = {};
        __builtin_amdgcn_s_setprio(1);
        #pragma unroll
        for (int hs = 0; hs < 8; hs++) {
          const int ch = hs * 2 + hi;
          f16x8 k0 = *(const f16x8*)(Kb + (hh2 * 64 + l31) * 256 + ((ch << 4) ^ sw7));
          f16x8 k1 = *(const f16x8*)(Kb + (hh2 * 64 + 32 + l31) * 256 + ((ch << 4) ^ sw7));
          S0 = __builtin_amdgcn_mfma_f32_32x32x16_f16(k0, qf[hs], S0, 0, 0, 0);
          S1 = __builtin_amdgcn_mfma_f32_32x32x16_f16(k1, qf[hs], S1, 0, 0, 0);
        }
        __builtin_amdgcn_s_setprio(0);

        const bool domask = (kv0 + 63 > qwb);
        float p0[16], p1[16];
        #pragma unroll
        for (int r = 0; r < 16; r++) {
          const int cr = (r & 3) + 8 * (r >> 2) + 4 * hi;
          float e0 = fexp2(S0[r] - M2);
          float e1 = fexp2(S1[r] - M2);
          if (domask) {
            if (kv0 + cr > qlane) e0 = 0.f;
            if (kv0 + 32 + cr > qlane) e1 = 0.f;
          }
          p0[r] = e0; p1[r] = e1;
          psum += e0 + e1;
        }

        unsigned int pkv[4][4];
        #pragma unroll
        for (int gg = 0; gg < 4; gg++) {
          pkv[0][gg] = pkrtz(p0[2 * gg], p0[2 * gg + 1]);
          pkv[1][gg] = pkrtz(p0[8 + 2 * gg], p0[9 + 2 * gg]);
          pkv[2][gg] = pkrtz(p1[2 * gg], p1[2 * gg + 1]);
          pkv[3][gg] = pkrtz(p1[8 + 2 * gg], p1[9 + 2 * gg]);
        }
        f16x8 pa[4];
        #pragma unroll
        for (int ksx = 0; ksx < 4; ksx++) {
          unsigned int a0 = pkv[ksx][0], a1 = pkv[ksx][1], a2 = pkv[ksx][2], a3 = pkv[ksx][3];
          unsigned int x0 = (unsigned int)__shfl_xor((int)a0, 32);
          unsigned int x1 = (unsigned int)__shfl_xor((int)a1, 32);
          unsigned int x2 = (unsigned int)__shfl_xor((int)a2, 32);
          unsigned int x3 = (unsigned int)__shfl_xor((int)a3, 32);
          uint4v dv;
          dv.x = hi ? x2 : a0;
          dv.y = hi ? x3 : a1;
          dv.z = hi ? a2 : x0;
          dv.w = hi ? a3 : x1;
          pa[ksx] = __builtin_bit_cast(f16x8, dv);
        }

        __builtin_amdgcn_s_setprio(1);
        #pragma unroll
        for (int ksx = 0; ksx < 4; ksx++) {
          const int ch = hh2 * 8 + ksx * 2 + hi;
          f16x8 v0 = *(const f16x8*)(Vb + (0 * 32 + l31) * 256 + ((ch << 4) ^ sw7));
          acc0 = __builtin_amdgcn_mfma_f32_32x32x16_f16(pa[ksx], v0, acc0, 0, 0, 0);
          f16x8 v1 = *(const f16x8*)(Vb + (1 * 32 + l31) * 256 + ((ch << 4) ^ sw7));
          acc1 = __builtin_amdgcn_mfma_f32_32x32x16_f16(pa[ksx], v1, acc1, 0, 0, 0);
          f16x8 v2 = *(const f16x8*)(Vb + (2 * 32 + l31) * 256 + ((ch << 4) ^ sw7));
          acc2 = __builtin_amdgcn_mfma_f32_32x32x16_f16(pa[ksx], v2, acc2, 0, 0, 0);
          f16x8 v3 = *(const f16x8*)(Vb + (3 * 32 + l31) * 256 + ((ch << 4) ^ sw7));
          acc3 = __builtin_amdgcn_mfma_f32_32x32x16_f16(pa[ksx], v3, acc3, 0, 0, 0);
        }
        __builtin_amdgcn_s_setprio(0);
      }
    }
    __syncthreads();
  }

  const float tot = psum + __shfl_xor(psum, 32);
  if (heavy) {
    const int slot = bu * 8 + (qt - 8);
    float* pPart = (half ? PartB : PartA) + (size_t)slot * 16384;
    float* sPart = (half ? psB : psA) + slot * 128;
    if (hi == 0) sPart[w * 32 + l31] = tot;
    #pragma unroll
    for (int r = 0; r < 16; r++) {
      const int cr = (r & 3) + 8 * (r >> 2) + 4 * hi;
      float* dst = pPart + (size_t)(w * 32 + cr) * 128 + l31;
      dst[0]  = acc0[r];
      dst[32] = acc1[r];
      dst[64] = acc2[r];
      dst[96] = acc3[r];
    }
  } else {
    const float inv = 1.f / tot;
    #pragma unroll
    for (int r = 0; r < 16; r++) {
      const int cr = (r & 3) + 8 * (r >> 2) + 4 * hi;
      const float ivr = __shfl(inv, cr);
      _Float16* dst = Ao + ((size_t)(b * SS + q0 + w * 32 + cr)) * MM + u * HH + l31;
      dst[0]  = (_Float16)(acc0[r] * ivr);
      dst[32] = (_Float16)(acc1[r] * ivr);
      dst[64] = (_Float16)(acc2[r] * ivr);
      dst[96] = (_Float16)(acc3[r] * ivr);
    }
  }
}

// ---------------- combine heavy-strip partials -> Ao f16 ----------------
__global__ __launch_bounds__(256) void k_fin(
    const float* __restrict__ PartA, const float* __restrict__ PartB,
    const float* __restrict__ psA, const float* __restrict__ psB,
    _Float16* __restrict__ Ao) {
  const int slot = blockIdx.x;
  const int bu = slot >> 3, st = slot & 7;
  const int b = bu >> 4, u = bu & 15;
  const int qt = st + 8;
  const float* pa = PartA + (size_t)slot * 16384;
  const float* pb = PartB + (size_t)slot * 16384;
  const float* sa = psA + slot * 128;
  const float* sb = psB + slot * 128;
  #pragma unroll
  for (int it = 0; it < 16; it++) {
    const int unit = it * 256 + threadIdx.x;
    const int qr = unit >> 5, cg = unit & 31;
    const float inv = 1.f / (sa[qr] + sb[qr]);
    f32x4 va = *(const f32x4*)(pa + qr * 128 + cg * 4);
    f32x4 vb = *(const f32x4*)(pb + qr * 128 + cg * 4);
    f16x4 o = { (_Float16)((va[0] + vb[0]) * inv), (_Float16)((va[1] + vb[1]) * inv),
                (_Float16)((va[2] + vb[2]) * inv), (_Float16)((va[3] + vb[3]) * inv) };
    *(f16x4*)(Ao + ((size_t)(b * SS + qt * 128 + qr)) * MM + u * HH + cg * 4) = o;
  }
}

// ---------------- launcher ----------------
extern "C" void kernel_launch(void* const* d_in, const int* in_sizes, int n_in,
                              void* d_out, int out_size, void* d_ws, size_t ws_size,
                              hipStream_t stream) {
  const float* hidden = (const float*)d_in[0];
  const float* Wq = (const float*)d_in[2];
  const float* Wk = (const float*)d_in[3];
  const float* Wv = (const float*)d_in[4];
  const float* Wo = (const float*)d_in[5];
  const float* q_scale = (const float*)d_in[6];
  const float* k_scale = (const float*)d_in[7];

  char* ws = (char*)d_ws;
  _Float16* Xb    = (_Float16*)(ws);               // 4096x2048      16.78 MB (dead after GEMM1)
  _Float16* Wqkvt = (_Float16*)(ws + 16777216);    // 3072x2048      12.58 MB
  _Float16* Wot   = (_Float16*)(ws + 29360128);    // 2048x2048       8.39 MB
  _Float16* qkv   = (_Float16*)(ws + 37748736);    // 4096x3072      25.17 MB (dead after normrope)
  _Float16* Qr    = (_Float16*)(ws + 62914560);    // 2x16x2048x128  16.78 MB
  _Float16* Kr    = (_Float16*)(ws + 79691776);    // 2x4x2048x128    4.19 MB
  _Float16* VtG   = (_Float16*)(ws + 83886080);    // 2x4x128x2048    4.19 MB
  _Float16* Ao    = (_Float16*)(ws + 88080384);    // 4096x2048      16.78 MB
  float*    PartB = (float*)(ws);                  // over Xb
  float*    PartA = (float*)(ws + 37748736);       // over qkv
  float*    psA   = (float*)(ws + 54525952);       // 128 KB
  float*    psB   = (float*)(ws + 54657024);       // 128 KB

  k_prep<<<dim3(64, 64, 6), dim3(256), 0, stream>>>(hidden, Wq, Wk, Wv, Wo, Xb, Wqkvt, Wot);
  k_gemm256<3, true><<<dim3(256), dim3(512), 0, stream>>>(Xb, Wqkvt, (void*)qkv, 16, 3072, 2048);
  k_normrope<<<dim3(4096, 6), dim3(256), 0, stream>>>(qkv, q_scale, k_scale, Qr, Kr, VtG);
  k_attn<<<dim3(32, 24), dim3(256), 0, stream>>>(Qr, Kr, VtG, q_scale, k_scale,
                                                 PartA, PartB, psA, psB, Ao);
  k_fin<<<dim3(256), dim3(256), 0, stream>>>(PartA, PartB, psA, psB, Ao);
  k_gemm256<2, false><<<dim3(256), dim3(512), 0, stream>>>(Ao, Wot, d_out, 16, 2048, 2048);
}

// Round 18
// 193.701 us; speedup vs baseline: 1.2752x; 1.0291x over previous
//
#include <hip/hip_runtime.h>
#include <stdint.h>

#define BB 2
#define SS 2048
#define MM 2048
#define NQ 16
#define NKV 4
#define HH 128
#define KVB 64

typedef __attribute__((ext_vector_type(4))) float f32x4;
typedef __attribute__((ext_vector_type(16))) float f32x16;
typedef _Float16 f16x8 __attribute__((ext_vector_type(8)));
typedef _Float16 f16x4 __attribute__((ext_vector_type(4)));
typedef _Float16 f16x2 __attribute__((ext_vector_type(2)));
typedef unsigned int uint4v __attribute__((ext_vector_type(4)));

__device__ __forceinline__ void gll16(const _Float16* g, _Float16* l) {
  __builtin_amdgcn_global_load_lds(
      (__attribute__((address_space(1))) void*)g,
      (__attribute__((address_space(3))) void*)l, 16, 0, 0);
}

__device__ __forceinline__ float fexp2(float x) {
#if __has_builtin(__builtin_amdgcn_exp2f)
  return __builtin_amdgcn_exp2f(x);   // raw v_exp_f32
#else
  float r;
  asm("v_exp_f32 %0, %1" : "=v"(r) : "v"(x));
  return r;
#endif
}

// sin/cos of (2*pi*rev) via raw v_sin/v_cos (input in revolutions, fract-reduced)
__device__ __forceinline__ float fsin2pi(float rev) {
  float f, s;
  asm("v_fract_f32 %0, %1" : "=v"(f) : "v"(rev));
  asm("v_sin_f32 %0, %1" : "=v"(s) : "v"(f));
  return s;
}
__device__ __forceinline__ float fcos2pi(float rev) {
  float f, c;
  asm("v_fract_f32 %0, %1" : "=v"(f) : "v"(rev));
  asm("v_cos_f32 %0, %1" : "=v"(c) : "v"(f));
  return c;
}

__device__ __forceinline__ unsigned int pkrtz(float a, float b) {
  return __builtin_bit_cast(unsigned int, __builtin_amdgcn_cvt_pkrtz(a, b));
}

// ------------- fused prep: z<4 -> WIDE weight transpose {Wq,Wk,Wv,Wo}; z>=4 -> f32->f16 ----
// Wide tiles: 128 (k) x 32 (n). Reads float4/lane (16B), writes f16x4/lane (8B).
__global__ __launch_bounds__(256) void k_prep(
    const float* __restrict__ hidden,
    const float* __restrict__ Wq, const float* __restrict__ Wk,
    const float* __restrict__ Wv, const float* __restrict__ Wo,
    _Float16* __restrict__ Xb,
    _Float16* __restrict__ Wqkvt, _Float16* __restrict__ Wot) {
  const int z = blockIdx.z;
  if (z >= 4) {  // hidden f32 -> f16
    const int bid = (z - 4) * 4096 + blockIdx.y * 64 + blockIdx.x;
    const int i = bid * 256 + threadIdx.x;
    float4 v = ((const float4*)hidden)[i];
    f16x4 o = { (_Float16)v.x, (_Float16)v.y, (_Float16)v.z, (_Float16)v.w };
    ((f16x4*)Xb)[i] = o;
    return;
  }
  if (blockIdx.x >= 16) return;                       // k-tiles: 2048/128
  if ((z == 1 || z == 2) && blockIdx.y >= 16) return; // n-tiles: 512/32
  const float* in = (z == 0) ? Wq : (z == 1) ? Wk : (z == 2) ? Wv : Wo;
  _Float16* out = (z == 3) ? Wot : Wqkvt;
  const int N_in = (z == 1 || z == 2) ? 512 : 2048;
  const int n_off = (z == 1) ? 2048 : (z == 2) ? 2560 : 0;

  __shared__ float tile[128][33];
  const int k0 = blockIdx.x * 128;
  const int n0 = blockIdx.y * 32;
  // read: 128 rows x 32 cols f32 = 1024 float4; 4 per thread
  {
    const int rr = threadIdx.x >> 3;        // 0..31 (row group base)
    const int c4 = threadIdx.x & 7;         // float4 slot in row
    #pragma unroll
    for (int it = 0; it < 4; ++it) {
      const int r = it * 32 + rr;
      const float4 v = *(const float4*)(&in[(size_t)(k0 + r) * N_in + n0 + c4 * 4]);
      tile[r][c4 * 4 + 0] = v.x;
      tile[r][c4 * 4 + 1] = v.y;
      tile[r][c4 * 4 + 2] = v.z;
      tile[r][c4 * 4 + 3] = v.w;
    }
  }
  __syncthreads();
  // write: 32 out-rows x 128 k f16; lane covers 4 k as f16x4
  {
    const int rw = threadIdx.x >> 5;        // 0..7 (out-row group base)
    const int lk = threadIdx.x & 31;        // lane -> k block of 4
    #pragma unroll
    for (int it = 0; it < 4; ++it) {
      const int r = it * 8 + rw;            // out row (n offset)
      f16x4 o = { (_Float16)tile[lk * 4 + 0][r], (_Float16)tile[lk * 4 + 1][r],
                  (_Float16)tile[lk * 4 + 2][r], (_Float16)tile[lk * 4 + 3][r] };
      *(f16x4*)(&out[(size_t)(n0 + r + n_off) * 2048 + k0 + lk * 4]) = o;
    }
  }
}

// ============ 256xBN MFMA GEMM, 2 merged phases per K-tile (round-13 state) ============
template <int FN, bool F16OUT>
__global__ __launch_bounds__(512, 2) void k_gemm256(
    const _Float16* __restrict__ A, const _Float16* __restrict__ Bt,
    void* __restrict__ Cout, int NT_M, int N, int K) {
  __shared__ _Float16 As[2][256 * 64];
  __shared__ _Float16 Bs[2][FN * 64 * 64];

  const int tid = threadIdx.x;
  const int w = tid >> 6;
  const int l = tid & 63;
  const int lr = l & 15;
  const int al4 = l >> 4;
  const int wr = w >> 2;
  const int wc = w & 3;
  const int swz = (lr & 7) << 4;

  const int nwg = gridDim.x;
  const int bid = blockIdx.x;
  const int sbid = (bid & 7) * (nwg >> 3) + (bid >> 3);
  const int bm = (sbid % NT_M) * 256;
  const int bn = (sbid / NT_M) * (FN * 64);
  const int KT = K >> 6;

  const int srow = tid >> 3;
  const int sch = (tid & 7) ^ (srow & 7);
  const _Float16* aSrc = A + (size_t)(bm + srow) * K + sch * 8;
  const _Float16* bSrc = Bt + (size_t)(bn + srow) * K + sch * 8;

  auto stA = [&](int buf, int r, int kt) {
    gll16(aSrc + (size_t)(r * 64) * K + kt * 64, &As[buf][r * 4096 + w * 512]);
  };
  auto stB = [&](int buf, int r, int kt) {
    gll16(bSrc + (size_t)(r * 64) * K + kt * 64, &Bs[buf][r * 4096 + w * 512]);
  };

  f32x4 acc[8][FN] = {};

  stA(0, 0, 0); stA(0, 1, 0); stA(0, 2, 0); stA(0, 3, 0);
  stB(0, 0, 0); stB(0, 1, 0);
  if (FN == 3) stB(0, 2, 0);
  if (KT > 1) {
    stA(1, 0, 1); stA(1, 2, 1); stB(1, 0, 1); stB(1, 1, 1);
    asm volatile("s_waitcnt vmcnt(4)" ::: "memory");
  } else {
    asm volatile("s_waitcnt vmcnt(0)" ::: "memory");
  }
  __builtin_amdgcn_s_barrier();

  for (int t = 0; t < KT; ++t) {
    const int cb = t & 1;
    const char* Ab = (const char*)&As[cb][0];
    const char* Bb = (const char*)&Bs[cb][0];
    f16x8 bF[FN][2];
    #pragma unroll
    for (int ph = 0; ph < 2; ++ph) {
      f16x8 aF[4][2];
      #pragma unroll
      for (int fm = 0; fm < 4; ++fm)
        #pragma unroll
        for (int ks = 0; ks < 2; ++ks) {
          const int row = wr * 128 + (ph * 4 + fm) * 16 + lr;
          aF[fm][ks] = *(const f16x8*)(Ab + row * 128 + (((ks * 4 + al4) * 16) ^ swz));
        }
      if (ph == 0) {
        #pragma unroll
        for (int fn = 0; fn < FN; ++fn)
          #pragma unroll
          for (int ks = 0; ks < 2; ++ks) {
            const int col = wc * (FN * 16) + fn * 16 + lr;
            bF[fn][ks] = *(const f16x8*)(Bb + col * 128 + (((ks * 4 + al4) * 16) ^ swz));
          }
      }
      if (ph == 0 && t + 1 < KT) {
        if (FN == 3) stB(cb ^ 1, 2, t + 1);
        stA(cb ^ 1, 1, t + 1); stA(cb ^ 1, 3, t + 1);
      }
      if (ph == 1 && t + 2 < KT) {
        stA(cb, 0, t + 2); stA(cb, 2, t + 2);
        stB(cb, 0, t + 2); stB(cb, 1, t + 2);
      }
      __builtin_amdgcn_s_barrier();
      asm volatile("s_waitcnt lgkmcnt(0)" ::: "memory");
      __builtin_amdgcn_sched_barrier(0);
      __builtin_amdgcn_s_setprio(1);
      #pragma unroll
      for (int fm = 0; fm < 4; ++fm)
        #pragma unroll
        for (int fn = 0; fn < FN; ++fn)
          #pragma unroll
          for (int ks = 0; ks < 2; ++ks)
            acc[ph * 4 + fm][fn] = __builtin_amdgcn_mfma_f32_16x16x32_f16(
                aF[fm][ks], bF[fn][ks], acc[ph * 4 + fm][fn], 0, 0, 0);
      __builtin_amdgcn_s_setprio(0);
      __builtin_amdgcn_sched_barrier(0);
      if (ph == 0) {
        __builtin_amdgcn_s_barrier();
      } else {
        if (t + 2 < KT) asm volatile("s_waitcnt vmcnt(4)" ::: "memory");
        else            asm volatile("s_waitcnt vmcnt(0)" ::: "memory");
        __builtin_amdgcn_s_barrier();
      }
    }
  }

  #pragma unroll
  for (int fm = 0; fm < 8; ++fm) {
    #pragma unroll
    for (int i = 0; i < 4; ++i) {
      const int row = bm + wr * 128 + fm * 16 + al4 * 4 + i;
      #pragma unroll
      for (int fn = 0; fn < FN; ++fn) {
        const int col = bn + wc * (FN * 16) + fn * 16 + lr;
        if (F16OUT)
          ((_Float16*)Cout)[(size_t)row * N + col] = (_Float16)acc[fm][fn][i];
        else
          ((float*)Cout)[(size_t)row * N + col] = acc[fm][fn][i];
      }
    }
  }
}

// ------- fused RMSNorm + RoPE + scatter (y<5) and V transpose (y==5), fast trig -------
__global__ __launch_bounds__(256) void k_normrope(
    const _Float16* __restrict__ qkv,
    const float* __restrict__ q_scale, const float* __restrict__ k_scale,
    _Float16* __restrict__ Qr, _Float16* __restrict__ Kr,
    _Float16* __restrict__ VtG) {
  __shared__ _Float16 vtile[32][33];
  if (blockIdx.y == 5) {   // V transpose
    if (blockIdx.x >= 2048) return;
    const int s0 = (blockIdx.x & 63) * 32;
    const int zz = blockIdx.x >> 6;
    const int h0 = (zz & 3) * 32;
    const int bv = zz >> 2;
    const int b = bv >> 2;
    const int hv = bv & 3;
    const int tx = threadIdx.x & 31;
    const int ty = threadIdx.x >> 5;
    #pragma unroll
    for (int r = ty; r < 32; r += 8)
      vtile[r][tx] = qkv[(size_t)(b * SS + s0 + r) * 3072 + 2560 + hv * 128 + h0 + tx];
    __syncthreads();
    #pragma unroll
    for (int r = ty; r < 32; r += 8)
      VtG[((size_t)bv * HH + h0 + r) * SS + s0 + tx] = vtile[tx][r];
    return;
  }
  const int row = blockIdx.x;
  const int b = row >> 11;
  const int s = row & 2047;
  const int hh = blockIdx.y * 4 + (threadIdx.x >> 6);
  const int l = threadIdx.x & 63;
  const _Float16* src = qkv + (size_t)row * 3072 + hh * 128 + l * 2;
  float x0 = (float)src[0];
  float x1 = (float)src[1];
  float ssum = x0 * x0 + x1 * x1;
  #pragma unroll
  for (int d = 1; d < 64; d <<= 1) ssum += __shfl_xor(ssum, d);
  const float rstd = rsqrtf(ssum * (1.f / 128.f) + 1e-6f);
  const float* scl = (hh < 16) ? q_scale : k_scale;
  x0 *= rstd * scl[2 * l];
  x1 *= rstd * scl[2 * l + 1];
  const float y0 = __shfl_xor(x0, 32);
  const float y1 = __shfl_xor(x1, 32);
  const int j0 = (2 * l) & 63;
  const float kLog = 0.20762050593046014f;          // log2(10000)/64
  const float inv2pi = 0.15915494309189535f;
  const float rev0 = (float)s * fexp2(-(float)j0 * kLog) * inv2pi;
  const float rev1 = (float)s * fexp2(-(float)(j0 + 1) * kLog) * inv2pi;
  const float c0 = fcos2pi(rev0), s0 = fsin2pi(rev0);
  const float c1 = fcos2pi(rev1), s1 = fsin2pi(rev1);
  float r0, r1;
  if (l < 32) { r0 = x0 * c0 - y0 * s0; r1 = x1 * c1 - y1 * s1; }
  else        { r0 = x0 * c0 + y0 * s0; r1 = x1 * c1 + y1 * s1; }
  if (hh < 16) {
    _Float16* dst = Qr + ((size_t)(b * NQ + hh) * SS + s) * HH + 2 * l;
    dst[0] = (_Float16)r0; dst[1] = (_Float16)r1;
  } else {
    _Float16* dst = Kr + ((size_t)(b * NKV + (hh - 16)) * SS + s) * HH + 2 * l;
    dst[0] = (_Float16)r0; dst[1] = (_Float16)r1;
  }
}

// ---- causal GQA flash attention: KVB=128 macro-tiles + XCD-group swizzle ----
__device__ const unsigned char g_tasks[24] = {
  61, 63, 28,
  57, 59, 53, 55, 24,
  49, 51, 45, 47, 20,
  41, 43, 37, 39, 16,
  33, 35, 12,
  8, 4, 0
};

__global__ __launch_bounds__(256, 2) void k_attn(
    const _Float16* __restrict__ Qr, const _Float16* __restrict__ Kr,
    const _Float16* __restrict__ VtG,
    const float* __restrict__ qs, const float* __restrict__ ks,
    float* __restrict__ PartA, float* __restrict__ PartB,
    float* __restrict__ psA, float* __restrict__ psB,
    _Float16* __restrict__ Ao) {
  __shared__ _Float16 Ks[128 * 128];   // 32KB
  __shared__ _Float16 Vs[128 * 128];   // 32KB

  const int tid = threadIdx.x;
  const int w = tid >> 6;
  const int l = tid & 63;
  const int l31 = l & 31;
  const int hi = l >> 5;
  const int sw7 = (l31 & 7) << 4;

  const int n = blockIdx.y * 32 + blockIdx.x;   // 0..767
  const int g = n & 7;
  const int slot9 = n >> 3;                     // 0..95
  const int j = slot9 & 3;
  const int b = g >> 2;
  const int kvh = g & 3;
  const int u = kvh * 4 + j;
  const int bu = b * 16 + u;

  const int task = g_tasks[slot9 >> 2];
  const int heavy = task & 1;
  const int half = (task >> 1) & 1;
  const int qt = task >> 2;
  const int q0 = qt * 128;
  const int total = 2 * qt + 2;
  const int h0 = ((qt + 2) >> 1) << 1;
  const int t0 = heavy ? (half ? h0 : 0) : 0;
  const int t1 = heavy ? (half ? total : h0) : total;

  float ma = fmaxf(fabsf(qs[l]), fabsf(qs[l + 64]));
  float mb = fmaxf(fabsf(ks[l]), fabsf(ks[l + 64]));
  #pragma unroll
  for (int d = 1; d < 64; d <<= 1) {
    ma = fmaxf(ma, __shfl_xor(ma, d));
    mb = fmaxf(mb, __shfl_xor(mb, d));
  }
  const float M2 = 1.4426950408889634f * ma * mb;
  const float K2 = 0.12752982260735795f; // log2(e)/sqrt(128)

  const _Float16* Kbase = Kr + (size_t)(b * NKV + kvh) * SS * HH;
  const _Float16* Vbase = VtG + (size_t)(b * NKV + kvh) * HH * SS;

  f16x8 qf[8];
  {
    const _Float16* qp = Qr + ((size_t)(b * NQ + u) * SS + q0 + w * 32 + l31) * HH + hi * 8;
    #pragma unroll
    for (int hs = 0; hs < 8; hs++) {
      qf[hs] = *(const f16x8*)(qp + hs * 16);
      qf[hs] *= (_Float16)K2;
    }
  }

  f32x16 acc0 = {}, acc1 = {}, acc2 = {}, acc3 = {};
  float psum = 0.f;

  auto stage = [&](int m) {
    const int kv0 = m * KVB;
    #pragma unroll
    for (int it = 0; it < 8; it++) {
      const int nn = it * 256 + tid;
      const int row = nn >> 4, c = nn & 15;
      const int cs = c ^ (row & 7);
      gll16(Kbase + (size_t)(kv0 + row) * HH + cs * 8,
            &Ks[(size_t)(it * 256 + w * 64) * 8]);
      gll16(Vbase + (size_t)row * SS + kv0 + cs * 8,
            &Vs[(size_t)(it * 256 + w * 64) * 8]);
    }
  };

  const int qwb = q0 + w * 32;
  const int qlane = qwb + l31;

  for (int m = t0; m < t1; m += 2) {
    stage(m);
    __syncthreads();
    const char* Kb = (const char*)&Ks[0];
    const char* Vb = (const char*)&Vs[0];
    #pragma unroll
    for (int hh2 = 0; hh2 < 2; ++hh2) {
      const int kv0 = m * KVB + hh2 * 64;
      if (kv0 <= qwb + 31) {
        f32x16 S0 = {}, S1 = {};
        __builtin_amdgcn_s_setprio(1);
        #pragma unroll
        for (int hs = 0; hs < 8; hs++) {
          const int ch = hs * 2 + hi;
          f16x8 k0 = *(const f16x8*)(Kb + (hh2 * 64 + l31) * 256 + ((ch << 4) ^ sw7));
          f16x8 k1 = *(const f16x8*)(Kb + (hh2 * 64 + 32 + l31) * 256 + ((ch << 4) ^ sw7));
          S0 = __builtin_amdgcn_mfma_f32_32x32x16_f16(k0, qf[hs], S0, 0, 0, 0);
          S1 = __builtin_amdgcn_mfma_f32_32x32x16_f16(k1, qf[hs], S1, 0, 0, 0);
        }
        __builtin_amdgcn_s_setprio(0);

        const bool domask = (kv0 + 63 > qwb);
        float p0[16], p1[16];
        #pragma unroll
        for (int r = 0; r < 16; r++) {
          const int cr = (r & 3) + 8 * (r >> 2) + 4 * hi;
          float e0 = fexp2(S0[r] - M2);
          float e1 = fexp2(S1[r] - M2);
          if (domask) {
            if (kv0 + cr > qlane) e0 = 0.f;
            if (kv0 + 32 + cr > qlane) e1 = 0.f;
          }
          p0[r] = e0; p1[r] = e1;
          psum += e0 + e1;
        }

        unsigned int pkv[4][4];
        #pragma unroll
        for (int gg = 0; gg < 4; gg++) {
          pkv[0][gg] = pkrtz(p0[2 * gg], p0[2 * gg + 1]);
          pkv[1][gg] = pkrtz(p0[8 + 2 * gg], p0[9 + 2 * gg]);
          pkv[2][gg] = pkrtz(p1[2 * gg], p1[2 * gg + 1]);
          pkv[3][gg] = pkrtz(p1[8 + 2 * gg], p1[9 + 2 * gg]);
        }
        f16x8 pa[4];
        #pragma unroll
        for (int ksx = 0; ksx < 4; ksx++) {
          unsigned int a0 = pkv[ksx][0], a1 = pkv[ksx][1], a2 = pkv[ksx][2], a3 = pkv[ksx][3];
          unsigned int x0 = (unsigned int)__shfl_xor((int)a0, 32);
          unsigned int x1 = (unsigned int)__shfl_xor((int)a1, 32);
          unsigned int x2 = (unsigned int)__shfl_xor((int)a2, 32);
          unsigned int x3 = (unsigned int)__shfl_xor((int)a3, 32);
          uint4v dv;
          dv.x = hi ? x2 : a0;
          dv.y = hi ? x3 : a1;
          dv.z = hi ? a2 : x0;
          dv.w = hi ? a3 : x1;
          pa[ksx] = __builtin_bit_cast(f16x8, dv);
        }

        __builtin_amdgcn_s_setprio(1);
        #pragma unroll
        for (int ksx = 0; ksx < 4; ksx++) {
          const int ch = hh2 * 8 + ksx * 2 + hi;
          f16x8 v0 = *(const f16x8*)(Vb + (0 * 32 + l31) * 256 + ((ch << 4) ^ sw7));
          acc0 = __builtin_amdgcn_mfma_f32_32x32x16_f16(pa[ksx], v0, acc0, 0, 0, 0);
          f16x8 v1 = *(const f16x8*)(Vb + (1 * 32 + l31) * 256 + ((ch << 4) ^ sw7));
          acc1 = __builtin_amdgcn_mfma_f32_32x32x16_f16(pa[ksx], v1, acc1, 0, 0, 0);
          f16x8 v2 = *(const f16x8*)(Vb + (2 * 32 + l31) * 256 + ((ch << 4) ^ sw7));
          acc2 = __builtin_amdgcn_mfma_f32_32x32x16_f16(pa[ksx], v2, acc2, 0, 0, 0);
          f16x8 v3 = *(const f16x8*)(Vb + (3 * 32 + l31) * 256 + ((ch << 4) ^ sw7));
          acc3 = __builtin_amdgcn_mfma_f32_32x32x16_f16(pa[ksx], v3, acc3, 0, 0, 0);
        }
        __builtin_amdgcn_s_setprio(0);
      }
    }
    __syncthreads();
  }

  const float tot = psum + __shfl_xor(psum, 32);
  if (heavy) {
    const int slot = bu * 8 + (qt - 8);
    float* pPart = (half ? PartB : PartA) + (size_t)slot * 16384;
    float* sPart = (half ? psB : psA) + slot * 128;
    if (hi == 0) sPart[w * 32 + l31] = tot;
    #pragma unroll
    for (int r = 0; r < 16; r++) {
      const int cr = (r & 3) + 8 * (r >> 2) + 4 * hi;
      float* dst = pPart + (size_t)(w * 32 + cr) * 128 + l31;
      dst[0]  = acc0[r];
      dst[32] = acc1[r];
      dst[64] = acc2[r];
      dst[96] = acc3[r];
    }
  } else {
    const float inv = 1.f / tot;
    #pragma unroll
    for (int r = 0; r < 16; r++) {
      const int cr = (r & 3) + 8 * (r >> 2) + 4 * hi;
      const float ivr = __shfl(inv, cr);
      _Float16* dst = Ao + ((size_t)(b * SS + q0 + w * 32 + cr)) * MM + u * HH + l31;
      dst[0]  = (_Float16)(acc0[r] * ivr);
      dst[32] = (_Float16)(acc1[r] * ivr);
      dst[64] = (_Float16)(acc2[r] * ivr);
      dst[96] = (_Float16)(acc3[r] * ivr);
    }
  }
}

// ---------------- combine heavy-strip partials -> Ao f16 ----------------
__global__ __launch_bounds__(256) void k_fin(
    const float* __restrict__ PartA, const float* __restrict__ PartB,
    const float* __restrict__ psA, const float* __restrict__ psB,
    _Float16* __restrict__ Ao) {
  const int slot = blockIdx.x;
  const int bu = slot >> 3, st = slot & 7;
  const int b = bu >> 4, u = bu & 15;
  const int qt = st + 8;
  const float* pa = PartA + (size_t)slot * 16384;
  const float* pb = PartB + (size_t)slot * 16384;
  const float* sa = psA + slot * 128;
  const float* sb = psB + slot * 128;
  #pragma unroll
  for (int it = 0; it < 16; it++) {
    const int unit = it * 256 + threadIdx.x;
    const int qr = unit >> 5, cg = unit & 31;
    const float inv = 1.f / (sa[qr] + sb[qr]);
    f32x4 va = *(const f32x4*)(pa + qr * 128 + cg * 4);
    f32x4 vb = *(const f32x4*)(pb + qr * 128 + cg * 4);
    f16x4 o = { (_Float16)((va[0] + vb[0]) * inv), (_Float16)((va[1] + vb[1]) * inv),
                (_Float16)((va[2] + vb[2]) * inv), (_Float16)((va[3] + vb[3]) * inv) };
    *(f16x4*)(Ao + ((size_t)(b * SS + qt * 128 + qr)) * MM + u * HH + cg * 4) = o;
  }
}

// ---------------- launcher ----------------
extern "C" void kernel_launch(void* const* d_in, const int* in_sizes, int n_in,
                              void* d_out, int out_size, void* d_ws, size_t ws_size,
                              hipStream_t stream) {
  const float* hidden = (const float*)d_in[0];
  const float* Wq = (const float*)d_in[2];
  const float* Wk = (const float*)d_in[3];
  const float* Wv = (const float*)d_in[4];
  const float* Wo = (const float*)d_in[5];
  const float* q_scale = (const float*)d_in[6];
  const float* k_scale = (const float*)d_in[7];

  char* ws = (char*)d_ws;
  _Float16* Xb    = (_Float16*)(ws);               // 4096x2048      16.78 MB (dead after GEMM1)
  _Float16* Wqkvt = (_Float16*)(ws + 16777216);    // 3072x2048      12.58 MB
  _Float16* Wot   = (_Float16*)(ws + 29360128);    // 2048x2048       8.39 MB
  _Float16* qkv   = (_Float16*)(ws + 37748736);    // 4096x3072      25.17 MB (dead after normrope)
  _Float16* Qr    = (_Float16*)(ws + 62914560);    // 2x16x2048x128  16.78 MB
  _Float16* Kr    = (_Float16*)(ws + 79691776);    // 2x4x2048x128    4.19 MB
  _Float16* VtG   = (_Float16*)(ws + 83886080);    // 2x4x128x2048    4.19 MB
  _Float16* Ao    = (_Float16*)(ws + 88080384);    // 4096x2048      16.78 MB
  float*    PartB = (float*)(ws);                  // over Xb
  float*    PartA = (float*)(ws + 37748736);       // over qkv
  float*    psA   = (float*)(ws + 54525952);       // 128 KB
  float*    psB   = (float*)(ws + 54657024);       // 128 KB

  k_prep<<<dim3(64, 64, 6), dim3(256), 0, stream>>>(hidden, Wq, Wk, Wv, Wo, Xb, Wqkvt, Wot);
  k_gemm256<3, true><<<dim3(256), dim3(512), 0, stream>>>(Xb, Wqkvt, (void*)qkv, 16, 3072, 2048);
  k_normrope<<<dim3(4096, 6), dim3(256), 0, stream>>>(qkv, q_scale, k_scale, Qr, Kr, VtG);
  k_attn<<<dim3(32, 24), dim3(256), 0, stream>>>(Qr, Kr, VtG, q_scale, k_scale,
                                                 PartA, PartB, psA, psB, Ao);
  k_fin<<<dim3(256), dim3(256), 0, stream>>>(PartA, PartB, psA, psB, Ao);
  k_gemm256<2, false><<<dim3(256), dim3(512), 0, stream>>>(Ao, Wot, d_out, 16, 2048, 2048);
}